// Round 14
// baseline (1196.564 us; speedup 1.0000x reference)
//
#include <hip/hip_runtime.h>

#define N_NODES  50000
#define NPAD     50048
#define N_EDGES  640000
#define IN_CH    64
#define EDGE_DIM 16
#define HID      128
#define HID2     256
#define NLAYER   5
#define NGRAPH   128
#define MT64     (NPAD / 64)
#define EPB      256   // edges per fused block

typedef unsigned short ushort_t;
typedef __attribute__((ext_vector_type(8))) short short8;
typedef __attribute__((ext_vector_type(4))) short s16x4;
typedef __attribute__((ext_vector_type(4))) float f32x4;
typedef __attribute__((ext_vector_type(2))) float f32x2;

__device__ __forceinline__ float b2f(ushort_t u) {
    union { unsigned v; float f; } x; x.v = ((unsigned)u) << 16; return x.f;
}
__device__ __forceinline__ ushort_t f2b(float f) {
    union { float f; unsigned u; } x; x.f = f;
    unsigned u = x.u;
    unsigned r = (u + 0x7FFFu + ((u >> 16) & 1u)) >> 16;
    return (ushort_t)r;
}

// ---------------- prep: transpose + f32->bf16 convert ----------------
__global__ void k_transpose_cvt(const float* __restrict__ src, ushort_t* __restrict__ dst,
                                int B, int K, int Nn) {
    long total = (long)B * K * Nn;
    for (long i = (long)blockIdx.x * blockDim.x + threadIdx.x; i < total;
         i += (long)gridDim.x * blockDim.x) {
        int b = (int)(i / ((long)K * Nn));
        int rem = (int)(i - (long)b * K * Nn);
        int k = rem / Nn;
        int n = rem - k * Nn;
        dst[(long)b * K * Nn + (long)n * K + k] = f2b(src[i]);
    }
}

// WcbT bf16 [l][col=128][k=32 zero-padded] + cc f32
__global__ __launch_bounds__(128) void k_combine(const float* __restrict__ ew,
                                                 const float* __restrict__ eb,
                                                 const float* __restrict__ lw,
                                                 const float* __restrict__ lb,
                                                 ushort_t* __restrict__ WcbT,
                                                 float* __restrict__ cc) {
    int l = blockIdx.x, j = threadIdx.x;
    float accW[EDGE_DIM];
#pragma unroll
    for (int k = 0; k < EDGE_DIM; ++k) accW[k] = 0.f;
    float accc = 0.f;
    for (int i = 0; i < HID; ++i) {
        float lwv = lw[((long)l * HID + i) * HID + j];
        accc = fmaf(eb[i], lwv, accc);
#pragma unroll
        for (int k = 0; k < EDGE_DIM; ++k)
            accW[k] = fmaf(ew[k * HID + i], lwv, accW[k]);
    }
    ushort_t* wp = WcbT + ((long)l * HID + j) * 32;
#pragma unroll
    for (int k = 0; k < EDGE_DIM; ++k) wp[k] = f2b(accW[k]);
#pragma unroll
    for (int k = EDGE_DIM; k < 32; ++k) wp[k] = 0;
    cc[l * HID + j] = accc + lb[l * HID + j];
}

// ---------------- CSR build ----------------
__global__ __launch_bounds__(256) void k_hist(const int* __restrict__ ei, int* __restrict__ deg) {
    int e = blockIdx.x * 256 + threadIdx.x;
    if (e < N_EDGES) atomicAdd(&deg[ei[N_EDGES + e]], 1);
}

__global__ __launch_bounds__(1024) void k_scan1(const int* __restrict__ deg,
                                                int* __restrict__ offs, int* __restrict__ bsum) {
    __shared__ int s[1024];
    int i = blockIdx.x * 1024 + threadIdx.x;
    int v = (i < N_NODES) ? deg[i] : 0;
    s[threadIdx.x] = v;
    __syncthreads();
    for (int off = 1; off < 1024; off <<= 1) {
        int t = (threadIdx.x >= off) ? s[threadIdx.x - off] : 0;
        __syncthreads();
        s[threadIdx.x] += t;
        __syncthreads();
    }
    if (i < N_NODES) offs[i] = s[threadIdx.x] - v;  // exclusive
    if (threadIdx.x == 1023) bsum[blockIdx.x] = s[1023];
}

__global__ void k_scan2(int* __restrict__ bsum, int nb) {
    if (threadIdx.x == 0 && blockIdx.x == 0) {
        int acc = 0;
        for (int i = 0; i < nb; ++i) { int v = bsum[i]; bsum[i] = acc; acc += v; }
    }
}

__global__ __launch_bounds__(1024) void k_scan3(int* __restrict__ offs, const int* __restrict__ bsum) {
    int i = blockIdx.x * 1024 + threadIdx.x;
    if (i < N_NODES) offs[i] += bsum[blockIdx.x];
}

// pos computation + 4B perm scatter only
__global__ __launch_bounds__(256) void k_scatter1(const int* __restrict__ ei,
                                                  const int* __restrict__ offs,
                                                  int* __restrict__ cursor,
                                                  int* __restrict__ perm) {
    int e = blockIdx.x * 256 + threadIdx.x;
    if (e >= N_EDGES) return;
    int d = ei[N_EDGES + e];
    int pos = offs[d] + atomicAdd(&cursor[d], 1);
    perm[pos] = e;
}

// gather reads, coalesced writes
__global__ __launch_bounds__(256) void k_gather(const int* __restrict__ perm,
                                                const int* __restrict__ ei,
                                                const float* __restrict__ ea,
                                                int* __restrict__ src_s,
                                                ushort_t* __restrict__ ea_sb) {
    int p = blockIdx.x * 256 + threadIdx.x;
    if (p >= N_EDGES) return;
    int e = perm[p];
    src_s[p] = ei[e];
    const f32x4* srcp = (const f32x4*)(ea + (long)e * EDGE_DIM);
    f32x4 v0 = srcp[0], v1 = srcp[1], v2 = srcp[2], v3 = srcp[3];
    short8 o0, o1;
#pragma unroll
    for (int j = 0; j < 4; ++j) {
        o0[j] = (short)f2b(v0[j]); o0[4 + j] = (short)f2b(v1[j]);
        o1[j] = (short)f2b(v2[j]); o1[4 + j] = (short)f2b(v3[j]);
    }
    short8* dst = (short8*)(ea_sb + (long)p * EDGE_DIM);
    dst[0] = o0;
    dst[1] = o1;
}

// ---------------- node encoder: h = relu(x @ node_w + node_b), f32 + bf16 out --------
__global__ __launch_bounds__(256) void k_node_enc(const float* __restrict__ x,
                                                  const ushort_t* __restrict__ w0T,
                                                  const float* __restrict__ nb,
                                                  float* __restrict__ h,
                                                  ushort_t* __restrict__ hb) {
    __shared__ __align__(16) short lB[HID * IN_CH];
    for (int c = threadIdx.x; c < HID * IN_CH / 8; c += 256) {
        int row = c >> 3, k0 = (c & 7) * 8;
        short8 v = *(const short8*)(w0T + row * IN_CH + k0);
        int g = (k0 >> 3) ^ (row & 7);
        *(short8*)&lB[row * IN_CH + g * 8] = v;
    }
    __syncthreads();
    int wv = threadIdx.x >> 6, l6 = threadIdx.x & 63;
    int lr = l6 & 15, lg = l6 >> 4;
    int grow = blockIdx.x * 64 + wv * 16 + lr;
    f32x4 acc[8];
#pragma unroll
    for (int nt = 0; nt < 8; ++nt) acc[nt] = (f32x4){0.f, 0.f, 0.f, 0.f};
#pragma unroll
    for (int kt = 0; kt < 2; ++kt) {
        int kk = kt * 32 + lg * 8;
        short8 a = {0, 0, 0, 0, 0, 0, 0, 0};
        if (grow < N_NODES) {
            const float* xr = x + (long)grow * IN_CH + kk;
            f32x4 v0 = *(const f32x4*)xr;
            f32x4 v1 = *(const f32x4*)(xr + 4);
#pragma unroll
            for (int j = 0; j < 4; ++j) { a[j] = (short)f2b(v0[j]); a[4 + j] = (short)f2b(v1[j]); }
        }
#pragma unroll
        for (int nt = 0; nt < 8; ++nt) {
            int brow = nt * 16 + lr;
            short8 b = *(const short8*)&lB[brow * IN_CH + (((kk >> 3) ^ (brow & 7)) << 3)];
            acc[nt] = __builtin_amdgcn_mfma_f32_16x16x32_bf16(a, b, acc[nt], 0, 0, 0);
        }
    }
    int orow0 = blockIdx.x * 64 + wv * 16 + lg * 4;
#pragma unroll
    for (int nt = 0; nt < 8; ++nt) {
        int col = nt * 16 + lr;
        float bias = nb[col];
#pragma unroll
        for (int r = 0; r < 4; ++r) {
            int row = orow0 + r;
            if (row < N_NODES) {
                float v = fmaxf(acc[nt][r] + bias, 0.f);
                h[(long)row * HID + col] = v;
                hb[(long)row * HID + col] = f2b(v);
            }
        }
    }
}

// ---------------- fused edge pass: MFMA messages -> LDS -> aggregate ----------------
// Block owns CSR edges [p0, p1). Interior nodes write z directly; boundary via zacc atomics.
__global__ __launch_bounds__(256) void k_edgefused(const ushort_t* __restrict__ ea_sb,
                                                   const ushort_t* __restrict__ WcbT,
                                                   const float* __restrict__ cc,
                                                   const int* __restrict__ src_s,
                                                   const int* __restrict__ offs,
                                                   const int* __restrict__ deg,
                                                   const float* __restrict__ h,
                                                   const ushort_t* __restrict__ hb,
                                                   const float* __restrict__ epsv,
                                                   float* __restrict__ zacc,
                                                   ushort_t* __restrict__ z, int l) {
    __shared__ __align__(16) ushort_t lG[EPB * HID];  // 64 KB message tile
    __shared__ int sNode[2];
    int p0 = blockIdx.x * EPB;
    int p1 = p0 + EPB < N_EDGES ? p0 + EPB : N_EDGES;
    int wv = threadIdx.x >> 6, l6 = threadIdx.x & 63;
    int lr = l6 & 15, lg = l6 >> 4;

    if (threadIdx.x == 0) {
        int lo = 0, hi = N_NODES - 1;
        while (lo < hi) { int mid = (lo + hi + 1) >> 1; if (offs[mid] <= p0) lo = mid; else hi = mid - 1; }
        sNode[0] = lo;
        int pm = p1 - 1;
        lo = 0; hi = N_NODES - 1;
        while (lo < hi) { int mid = (lo + hi + 1) >> 1; if (offs[mid] <= pm) lo = mid; else hi = mid - 1; }
        sNode[1] = lo;
    }

    // phase 1: messages into LDS (weights = A, edge attrs = B; packed per-edge stores)
    {
        short8 af[8];
        f32x4 cv[8];
        const ushort_t* wp = WcbT + (long)l * HID * 32;
#pragma unroll
        for (int nt = 0; nt < 8; ++nt) {
            af[nt] = *(const short8*)(wp + (nt * 16 + lr) * 32 + lg * 8);
            cv[nt] = *(const f32x4*)(cc + l * HID + nt * 16 + lg * 4);
        }
#pragma unroll
        for (int it = 0; it < 4; ++it) {
            int e = p0 + wv * 64 + it * 16 + lr;
            short8 b = {0, 0, 0, 0, 0, 0, 0, 0};
            if (e < p1 && lg < 2) b = *(const short8*)(ea_sb + (long)e * EDGE_DIM + lg * 8);
            f32x4 acc[8];
#pragma unroll
            for (int nt = 0; nt < 8; ++nt) acc[nt] = (f32x4){0.f, 0.f, 0.f, 0.f};
#pragma unroll
            for (int nt = 0; nt < 8; ++nt)
                acc[nt] = __builtin_amdgcn_mfma_f32_16x16x32_bf16(af[nt], b, acc[nt], 0, 0, 0);
            if (e < p1) {
                int el = e - p0;
#pragma unroll
                for (int nt = 0; nt < 8; ++nt) {
                    int chb = nt * 16 + lg * 4;
                    int chs = chb ^ ((el & 7) << 2);  // swizzle (4-elem granule)
                    s16x4 o;
#pragma unroll
                    for (int r = 0; r < 4; ++r) o[r] = (short)f2b(acc[nt][r] + cv[nt][r]);
                    *(s16x4*)&lG[el * HID + chs] = o;
                }
            }
        }
    }
    __syncthreads();

    // phase 2: aggregate per node (2 ch/lane, wave per node, round-robin)
    int n_lo = sNode[0], n_hi = sNode[1];
    int ch0 = l6 * 2;
    int base4 = ch0 & ~3, coff = ch0 & 3;
    float ep1 = 1.f + epsv[l];
    for (int n = n_lo + wv; n <= n_hi; n += 4) {
        int o_n = offs[n], d_n = deg[n];
        int e_lo = o_n > p0 ? o_n : p0;
        int e_hi = (o_n + d_n) < p1 ? (o_n + d_n) : p1;
        float a0 = 0.f, a1 = 0.f;
        int i = e_lo;
        for (; i + 4 <= e_hi; i += 4) {
            int sa = src_s[i], sb_ = src_s[i + 1], sc_ = src_s[i + 2], sd_ = src_s[i + 3];
            unsigned ha = *(const unsigned*)(hb + (long)sa * HID + ch0);
            unsigned hbv = *(const unsigned*)(hb + (long)sb_ * HID + ch0);
            unsigned hc = *(const unsigned*)(hb + (long)sc_ * HID + ch0);
            unsigned hd = *(const unsigned*)(hb + (long)sd_ * HID + ch0);
#pragma unroll
            for (int j = 0; j < 4; ++j) {
                int el = i + j - p0;
                unsigned gv = *(const unsigned*)&lG[el * HID + (base4 ^ ((el & 7) << 2)) + coff];
                unsigned hv = (j == 0) ? ha : (j == 1) ? hbv : (j == 2) ? hc : hd;
                a0 += fmaxf(b2f((ushort_t)(hv & 0xffff)) + b2f((ushort_t)(gv & 0xffff)), 0.f);
                a1 += fmaxf(b2f((ushort_t)(hv >> 16)) + b2f((ushort_t)(gv >> 16)), 0.f);
            }
        }
        for (; i < e_hi; ++i) {
            int s = src_s[i];
            unsigned hv = *(const unsigned*)(hb + (long)s * HID + ch0);
            int el = i - p0;
            unsigned gv = *(const unsigned*)&lG[el * HID + (base4 ^ ((el & 7) << 2)) + coff];
            a0 += fmaxf(b2f((ushort_t)(hv & 0xffff)) + b2f((ushort_t)(gv & 0xffff)), 0.f);
            a1 += fmaxf(b2f((ushort_t)(hv >> 16)) + b2f((ushort_t)(gv >> 16)), 0.f);
        }
        bool interior = (o_n >= p0) && (o_n + d_n <= p1);
        if (interior) {
            f32x2 hn = *(const f32x2*)(h + (long)n * HID + ch0);
            unsigned zz = (unsigned)f2b(fmaf(ep1, hn[0], a0)) |
                          ((unsigned)f2b(fmaf(ep1, hn[1], a1)) << 16);
            *(unsigned*)(z + (long)n * HID + ch0) = zz;
        } else if (e_lo < e_hi) {
            atomicAdd(&zacc[(long)n * HID + ch0], a0);
            atomicAdd(&zacc[(long)n * HID + ch0 + 1], a1);
        }
    }
}

// finalize boundary + deg-0 nodes; reset their zacc rows to 0 for the next layer
__global__ __launch_bounds__(256) void k_edgefin(const int* __restrict__ offs,
                                                 const int* __restrict__ deg,
                                                 const float* __restrict__ h,
                                                 const float* __restrict__ epsv,
                                                 float* __restrict__ zacc,
                                                 ushort_t* __restrict__ z, int l) {
    int lane = threadIdx.x & 63;
    int node = blockIdx.x * 4 + (threadIdx.x >> 6);
    if (node >= N_NODES) return;
    int o = offs[node], d = deg[node];
    bool boundary = (d == 0) || ((o / EPB) != ((o + d - 1) / EPB));
    if (!boundary) return;
    int ch0 = lane * 2;
    long base = (long)node * HID + ch0;
    f32x2 za = *(const f32x2*)(zacc + base);
    float ep1 = 1.f + epsv[l];
    f32x2 hn = *(const f32x2*)(h + base);
    unsigned zz = (unsigned)f2b(fmaf(ep1, hn[0], za[0])) |
                  ((unsigned)f2b(fmaf(ep1, hn[1], za[1])) << 16);
    *(unsigned*)(z + base) = zz;
    *(f32x2*)(zacc + base) = (f32x2){0.f, 0.f};
}

// ---------------- mlp1: one 64-node tile/block, LDS weight half (A), packed stores ----
__global__ __launch_bounds__(256) void k_mlp1(const ushort_t* __restrict__ z,
                                              const ushort_t* __restrict__ w1T,
                                              const float* __restrict__ b1,
                                              ushort_t* __restrict__ ibuf, int l) {
    __shared__ __align__(16) short lBw[128 * HID];  // 32 KB: 128 feats x K=128
    int half = blockIdx.x & 1;
    int tile = blockIdx.x >> 1;  // [0, MT64)
    const ushort_t* wl = w1T + (long)l * HID2 * HID + (long)half * 128 * HID;
    for (int c = threadIdx.x; c < 128 * HID / 8; c += 256) {
        int row = c >> 4, k0 = (c & 15) * 8;
        short8 v = *(const short8*)(wl + row * HID + k0);
        int gsw = (k0 >> 3) ^ (row & 7);
        *(short8*)&lBw[row * HID + gsw * 8] = v;
    }
    int wv = threadIdx.x >> 6, l6 = threadIdx.x & 63;
    int lr = l6 & 15, lg = l6 >> 4;
    int node = tile * 64 + wv * 16 + lr;
    short8 b[4];
    const ushort_t* zr = z + (long)node * HID;
#pragma unroll
    for (int kt = 0; kt < 4; ++kt) b[kt] = *(const short8*)(zr + kt * 32 + lg * 8);
    __syncthreads();
#pragma unroll
    for (int nt = 0; nt < 8; ++nt) {
        f32x4 acc = (f32x4){0.f, 0.f, 0.f, 0.f};
        int brow = nt * 16 + lr;
#pragma unroll
        for (int kt = 0; kt < 4; ++kt) {
            short8 af = *(const short8*)&lBw[brow * HID + (((kt * 4 + lg) ^ (brow & 7)) << 3)];
            acc = __builtin_amdgcn_mfma_f32_16x16x32_bf16(af, b[kt], acc, 0, 0, 0);
        }
        f32x4 bv = *(const f32x4*)(b1 + l * HID2 + half * 128 + nt * 16 + lg * 4);
        s16x4 o;
#pragma unroll
        for (int r = 0; r < 4; ++r) o[r] = (short)f2b(fmaxf(acc[r] + bv[r], 0.f));
        *(s16x4*)(ibuf + (long)node * HID2 + half * 128 + nt * 16 + lg * 4) = o;
    }
}

// ---------------- mlp2: one 64-node tile/block, LDS weight half (A), BN stats via LDS ----
__global__ __launch_bounds__(256) void k_mlp2(const ushort_t* __restrict__ ibuf,
                                              const ushort_t* __restrict__ w2T,
                                              const float* __restrict__ b2,
                                              ushort_t* __restrict__ z2,
                                              float* __restrict__ bnstats, int l) {
    __shared__ __align__(16) short lBw[64 * HID2];  // 32 KB: 64 feats x K=256
    __shared__ float lStat[2][64];
    int half = blockIdx.x & 1;
    int tile = blockIdx.x >> 1;
    const ushort_t* wl = w2T + (long)l * HID * HID2 + (long)half * 64 * HID2;
    for (int c = threadIdx.x; c < 64 * HID2 / 8; c += 256) {
        int row = c >> 5, k0 = (c & 31) * 8;
        short8 v = *(const short8*)(wl + row * HID2 + k0);
        int gsw = (k0 >> 3) ^ (row & 7);
        *(short8*)&lBw[row * HID2 + gsw * 8] = v;
    }
    if (threadIdx.x < 128) lStat[threadIdx.x >> 6][threadIdx.x & 63] = 0.f;
    int wv = threadIdx.x >> 6, l6 = threadIdx.x & 63;
    int lr = l6 & 15, lg = l6 >> 4;
    int node = tile * 64 + wv * 16 + lr;
    bool valid = node < N_NODES;
    short8 b[8];
    const ushort_t* ir = ibuf + (long)node * HID2;
#pragma unroll
    for (int kt = 0; kt < 8; ++kt) b[kt] = *(const short8*)(ir + kt * 32 + lg * 8);
    __syncthreads();
#pragma unroll
    for (int nt = 0; nt < 4; ++nt) {
        f32x4 acc = (f32x4){0.f, 0.f, 0.f, 0.f};
        int brow = nt * 16 + lr;
#pragma unroll
        for (int kt = 0; kt < 8; ++kt) {
            short8 af = *(const short8*)&lBw[brow * HID2 + (((kt * 4 + lg) ^ (brow & 7)) << 3)];
            acc = __builtin_amdgcn_mfma_f32_16x16x32_bf16(af, b[kt], acc, 0, 0, 0);
        }
        f32x4 bv = *(const f32x4*)(b2 + l * HID + half * 64 + nt * 16 + lg * 4);
        s16x4 o;
#pragma unroll
        for (int r = 0; r < 4; ++r) {
            float v = acc[r] + bv[r];
            o[r] = (short)f2b(v);
            float s = valid ? v : 0.f, q = valid ? v * v : 0.f;
            s += __shfl_xor(s, 1); s += __shfl_xor(s, 2);
            s += __shfl_xor(s, 4); s += __shfl_xor(s, 8);
            q += __shfl_xor(q, 1); q += __shfl_xor(q, 2);
            q += __shfl_xor(q, 4); q += __shfl_xor(q, 8);
            if (lr == 0) {
                int f = nt * 16 + lg * 4 + r;  // feat within half [0,64)
                atomicAdd(&lStat[0][f], s);
                atomicAdd(&lStat[1][f], q);
            }
        }
        *(s16x4*)(z2 + (long)node * HID + half * 64 + nt * 16 + lg * 4) = o;
    }
    __syncthreads();
    if (threadIdx.x < 128) {
        int which = threadIdx.x >> 6, f = threadIdx.x & 63;
        atomicAdd(&bnstats[(which * NLAYER + l) * HID + half * 64 + f], lStat[which][f]);
    }
}

// ---------------- BN apply + residual + relu ----------------
__global__ __launch_bounds__(1024) void k_resid(const ushort_t* __restrict__ z2,
                                                const float* __restrict__ bnstats,
                                                const float* __restrict__ bng,
                                                const float* __restrict__ bnb,
                                                float* __restrict__ h,
                                                ushort_t* __restrict__ hb, int l) {
    long i = (long)blockIdx.x * 1024 + threadIdx.x;
    int c = (int)(i & (HID - 1));
    float inv = 1.f / (float)N_NODES;
    float mu = bnstats[l * HID + c] * inv;
    float var = bnstats[(NLAYER + l) * HID + c] * inv - mu * mu;
    float A = rsqrtf(var + 1e-5f) * bng[l * HID + c];
    float B = bnb[l * HID + c] - mu * A;
    float v = fmaf(b2f(z2[i]), A, B) + h[i];
    v = fmaxf(v, 0.f);
    h[i] = v;
    hb[i] = f2b(v);
}

// ---------------- pooling ----------------
__global__ void k_gstart(const int* __restrict__ batch, int* __restrict__ gstart) {
    int g = threadIdx.x;
    if (g > NGRAPH) return;
    int lo = 0, hi = N_NODES;
    while (lo < hi) { int mid = (lo + hi) >> 1; if (batch[mid] < g) lo = mid + 1; else hi = mid; }
    gstart[g] = lo;
}

__global__ __launch_bounds__(512) void k_pool(const float* __restrict__ h,
                                              const int* __restrict__ gstart,
                                              float* __restrict__ pooled,
                                              float* __restrict__ outp) {
    __shared__ float red[4][HID];
    int g = blockIdx.x;
    int ch = threadIdx.x & 127, seg = threadIdx.x >> 7;
    int st = gstart[g], en = gstart[g + 1];
    float s = 0.f;
    for (int i = st + seg; i < en; i += 4) s += h[(long)i * HID + ch];
    red[seg][ch] = s;
    __syncthreads();
    if (seg == 0) {
        float p = (red[0][ch] + red[1][ch] + red[2][ch] + red[3][ch]) /
                  fmaxf((float)(en - st), 1.f);
        pooled[g * HID + ch] = p;
        outp[g * HID + ch] = p;
    }
}

// ---------------- output MLP ----------------
__global__ __launch_bounds__(128) void k_outmlp(const float* __restrict__ pooled,
                                                const float* __restrict__ w1,
                                                const float* __restrict__ b1,
                                                const float* __restrict__ w2,
                                                const float* __restrict__ b2,
                                                float* __restrict__ outl) {
    __shared__ float pr[HID];
    __shared__ float hid[64];
    int g = blockIdx.x, t = threadIdx.x;
    pr[t] = pooled[g * HID + t];
    __syncthreads();
    if (t < 64) {
        float a = b1[t];
        for (int k = 0; k < HID; ++k) a = fmaf(pr[k], w1[k * 64 + t], a);
        hid[t] = fmaxf(a, 0.f);
    }
    __syncthreads();
    float a = b2[t];
#pragma unroll
    for (int j = 0; j < 64; ++j) a = fmaf(hid[j], w2[j * HID + t], a);
    outl[g * HID + t] = a;
}

// =====================================================================================
extern "C" void kernel_launch(void* const* d_in, const int* in_sizes, int n_in,
                              void* d_out, int out_size, void* d_ws, size_t ws_size,
                              hipStream_t stream) {
    (void)in_sizes; (void)n_in; (void)out_size; (void)ws_size;
    const float* x      = (const float*)d_in[0];
    const int*   ei     = (const int*)d_in[1];
    const float* ea     = (const float*)d_in[2];
    const int*   batch  = (const int*)d_in[3];
    const float* node_w = (const float*)d_in[4];
    const float* node_b = (const float*)d_in[5];
    const float* edge_w = (const float*)d_in[6];
    const float* edge_b = (const float*)d_in[7];
    const float* epsv   = (const float*)d_in[8];
    const float* lin_w  = (const float*)d_in[9];
    const float* lin_b  = (const float*)d_in[10];
    const float* m1w    = (const float*)d_in[11];
    const float* m1b    = (const float*)d_in[12];
    const float* m2w    = (const float*)d_in[13];
    const float* m2b    = (const float*)d_in[14];
    const float* bng    = (const float*)d_in[15];
    const float* bnb    = (const float*)d_in[16];
    const float* ow1    = (const float*)d_in[17];
    const float* ob1    = (const float*)d_in[18];
    const float* ow2    = (const float*)d_in[19];
    const float* ob2    = (const float*)d_in[20];

    char* ws = (char*)d_ws;
    size_t off = 0;
    auto alloc = [&](size_t bytes) -> char* {
        char* p = ws + off;
        off = (off + bytes + 255) & ~(size_t)255;
        return p;
    };
    float*    h       = (float*)alloc((size_t)NPAD * HID * 4);
    ushort_t* hb      = (ushort_t*)alloc((size_t)NPAD * HID * 2);
    ushort_t* z       = (ushort_t*)alloc((size_t)NPAD * HID * 2);   // reused as z2
    ushort_t* ibuf    = (ushort_t*)alloc((size_t)NPAD * HID2 * 2);  // perm aliases this
    float*    zacc    = (float*)alloc((size_t)NPAD * HID * 4);
    ushort_t* ea_sb   = (ushort_t*)alloc((size_t)N_EDGES * EDGE_DIM * 2 + 64);
    int*      src_s   = (int*)alloc((size_t)N_EDGES * 4);
    int*      deg     = (int*)alloc((size_t)N_NODES * 4);
    int*      offs    = (int*)alloc((size_t)N_NODES * 4);
    int*      cursor  = (int*)alloc((size_t)N_NODES * 4);
    int*      bsum    = (int*)alloc(64 * 4);
    ushort_t* WcbT    = (ushort_t*)alloc((size_t)NLAYER * HID * 32 * 2);
    float*    cc      = (float*)alloc((size_t)NLAYER * HID * 4);
    ushort_t* w0T     = (ushort_t*)alloc((size_t)HID * IN_CH * 2);
    ushort_t* w1T     = (ushort_t*)alloc((size_t)NLAYER * HID2 * HID * 2);
    ushort_t* w2T     = (ushort_t*)alloc((size_t)NLAYER * HID * HID2 * 2);
    float*    bnstats = (float*)alloc((size_t)2 * NLAYER * HID * 4);
    int*      gstart  = (int*)alloc((NGRAPH + 1) * 4);
    float*    pooled  = (float*)alloc((size_t)NGRAPH * HID * 4);
    int*      perm    = (int*)ibuf;   // alias: used only during CSR build
    ushort_t* z2      = z;

    (void)hipMemsetAsync(deg, 0, (size_t)N_NODES * 4, stream);
    (void)hipMemsetAsync(cursor, 0, (size_t)N_NODES * 4, stream);
    (void)hipMemsetAsync(bnstats, 0, (size_t)2 * NLAYER * HID * 4, stream);
    (void)hipMemsetAsync(zacc, 0, (size_t)NPAD * HID * 4, stream);

    k_transpose_cvt<<<64, 256, 0, stream>>>(node_w, w0T, 1, IN_CH, HID);
    k_transpose_cvt<<<640, 256, 0, stream>>>(m1w, w1T, NLAYER, HID, HID2);
    k_transpose_cvt<<<640, 256, 0, stream>>>(m2w, w2T, NLAYER, HID2, HID);
    k_combine<<<NLAYER, HID, 0, stream>>>(edge_w, edge_b, lin_w, lin_b, WcbT, cc);

    k_hist<<<N_EDGES / 256, 256, 0, stream>>>(ei, deg);
    k_scan1<<<49, 1024, 0, stream>>>(deg, offs, bsum);
    k_scan2<<<1, 1, 0, stream>>>(bsum, 49);
    k_scan3<<<49, 1024, 0, stream>>>(offs, bsum);
    k_scatter1<<<N_EDGES / 256, 256, 0, stream>>>(ei, offs, cursor, perm);
    k_gather<<<N_EDGES / 256, 256, 0, stream>>>(perm, ei, ea, src_s, ea_sb);

    k_node_enc<<<NPAD / 64, 256, 0, stream>>>(x, w0T, node_b, h, hb);

    int nfused = (N_EDGES + EPB - 1) / EPB;
    for (int l = 0; l < NLAYER; ++l) {
        k_edgefused<<<nfused, 256, 0, stream>>>(ea_sb, WcbT, cc, src_s, offs, deg,
                                                h, hb, epsv, zacc, z, l);
        k_edgefin<<<(N_NODES + 3) / 4, 256, 0, stream>>>(offs, deg, h, epsv, zacc, z, l);
        k_mlp1<<<MT64 * 2, 256, 0, stream>>>(z, w1T, m1b, ibuf, l);
        k_mlp2<<<MT64 * 2, 256, 0, stream>>>(ibuf, w2T, m2b, z2, bnstats, l);
        k_resid<<<(N_NODES * HID) / 1024, 1024, 0, stream>>>(z2, bnstats, bng, bnb, h, hb, l);
    }

    k_gstart<<<1, 256, 0, stream>>>(batch, gstart);
    k_pool<<<NGRAPH, 512, 0, stream>>>(h, gstart, pooled, (float*)d_out + NGRAPH * HID);
    k_outmlp<<<NGRAPH, HID, 0, stream>>>(pooled, ow1, ob1, ow2, ob2, (float*)d_out);
}

// Round 15
// 1089.992 us; speedup vs baseline: 1.0978x; 1.0978x over previous
//
#include <hip/hip_runtime.h>

#define N_NODES  50000
#define NPAD     50048
#define N_EDGES  640000
#define IN_CH    64
#define EDGE_DIM 16
#define HID      128
#define HID2     256
#define NLAYER   5
#define NGRAPH   128
#define MT64     (NPAD / 64)

typedef unsigned short ushort_t;
typedef __attribute__((ext_vector_type(8))) short short8;
typedef __attribute__((ext_vector_type(4))) short s16x4;
typedef __attribute__((ext_vector_type(4))) float f32x4;
typedef __attribute__((ext_vector_type(2))) float f32x2;

__device__ __forceinline__ float b2f(ushort_t u) {
    union { unsigned v; float f; } x; x.v = ((unsigned)u) << 16; return x.f;
}
__device__ __forceinline__ ushort_t f2b(float f) {
    union { float f; unsigned u; } x; x.f = f;
    unsigned u = x.u;
    unsigned r = (u + 0x7FFFu + ((u >> 16) & 1u)) >> 16;
    return (ushort_t)r;
}

// ---------------- prep: transpose + f32->bf16 convert ----------------
__global__ void k_transpose_cvt(const float* __restrict__ src, ushort_t* __restrict__ dst,
                                int B, int K, int Nn) {
    long total = (long)B * K * Nn;
    for (long i = (long)blockIdx.x * blockDim.x + threadIdx.x; i < total;
         i += (long)gridDim.x * blockDim.x) {
        int b = (int)(i / ((long)K * Nn));
        int rem = (int)(i - (long)b * K * Nn);
        int k = rem / Nn;
        int n = rem - k * Nn;
        dst[(long)b * K * Nn + (long)n * K + k] = f2b(src[i]);
    }
}

// WcbT bf16 [l][col=128][k=32 zero-padded] + cc f32
__global__ __launch_bounds__(128) void k_combine(const float* __restrict__ ew,
                                                 const float* __restrict__ eb,
                                                 const float* __restrict__ lw,
                                                 const float* __restrict__ lb,
                                                 ushort_t* __restrict__ WcbT,
                                                 float* __restrict__ cc) {
    int l = blockIdx.x, j = threadIdx.x;
    float accW[EDGE_DIM];
#pragma unroll
    for (int k = 0; k < EDGE_DIM; ++k) accW[k] = 0.f;
    float accc = 0.f;
    for (int i = 0; i < HID; ++i) {
        float lwv = lw[((long)l * HID + i) * HID + j];
        accc = fmaf(eb[i], lwv, accc);
#pragma unroll
        for (int k = 0; k < EDGE_DIM; ++k)
            accW[k] = fmaf(ew[k * HID + i], lwv, accW[k]);
    }
    ushort_t* wp = WcbT + ((long)l * HID + j) * 32;
#pragma unroll
    for (int k = 0; k < EDGE_DIM; ++k) wp[k] = f2b(accW[k]);
#pragma unroll
    for (int k = EDGE_DIM; k < 32; ++k) wp[k] = 0;
    cc[l * HID + j] = accc + lb[l * HID + j];
}

// ---------------- CSR build ----------------
__global__ __launch_bounds__(256) void k_hist(const int* __restrict__ ei, int* __restrict__ deg) {
    int e = blockIdx.x * 256 + threadIdx.x;
    if (e < N_EDGES) atomicAdd(&deg[ei[N_EDGES + e]], 1);
}

__global__ __launch_bounds__(1024) void k_scan1(const int* __restrict__ deg,
                                                int* __restrict__ offs, int* __restrict__ bsum) {
    __shared__ int s[1024];
    int i = blockIdx.x * 1024 + threadIdx.x;
    int v = (i < N_NODES) ? deg[i] : 0;
    s[threadIdx.x] = v;
    __syncthreads();
    for (int off = 1; off < 1024; off <<= 1) {
        int t = (threadIdx.x >= off) ? s[threadIdx.x - off] : 0;
        __syncthreads();
        s[threadIdx.x] += t;
        __syncthreads();
    }
    if (i < N_NODES) offs[i] = s[threadIdx.x] - v;  // exclusive
    if (threadIdx.x == 1023) bsum[blockIdx.x] = s[1023];
}

__global__ void k_scan2(int* __restrict__ bsum, int nb) {
    if (threadIdx.x == 0 && blockIdx.x == 0) {
        int acc = 0;
        for (int i = 0; i < nb; ++i) { int v = bsum[i]; bsum[i] = acc; acc += v; }
    }
}

__global__ __launch_bounds__(1024) void k_scan3(int* __restrict__ offs, const int* __restrict__ bsum) {
    int i = blockIdx.x * 1024 + threadIdx.x;
    if (i < N_NODES) offs[i] += bsum[blockIdx.x];
}

// pos computation + 4B perm scatter only
__global__ __launch_bounds__(256) void k_scatter1(const int* __restrict__ ei,
                                                  const int* __restrict__ offs,
                                                  int* __restrict__ cursor,
                                                  int* __restrict__ perm) {
    int e = blockIdx.x * 256 + threadIdx.x;
    if (e >= N_EDGES) return;
    int d = ei[N_EDGES + e];
    int pos = offs[d] + atomicAdd(&cursor[d], 1);
    perm[pos] = e;
}

// gather reads, coalesced writes
__global__ __launch_bounds__(256) void k_gather(const int* __restrict__ perm,
                                                const int* __restrict__ ei,
                                                const float* __restrict__ ea,
                                                int* __restrict__ src_s,
                                                ushort_t* __restrict__ ea_sb) {
    int p = blockIdx.x * 256 + threadIdx.x;
    if (p >= N_EDGES) return;
    int e = perm[p];
    src_s[p] = ei[e];
    const f32x4* srcp = (const f32x4*)(ea + (long)e * EDGE_DIM);
    f32x4 v0 = srcp[0], v1 = srcp[1], v2 = srcp[2], v3 = srcp[3];
    short8 o0, o1;
#pragma unroll
    for (int j = 0; j < 4; ++j) {
        o0[j] = (short)f2b(v0[j]); o0[4 + j] = (short)f2b(v1[j]);
        o1[j] = (short)f2b(v2[j]); o1[4 + j] = (short)f2b(v3[j]);
    }
    short8* dst = (short8*)(ea_sb + (long)p * EDGE_DIM);
    dst[0] = o0;
    dst[1] = o1;
}

// ---------------- node encoder: h = relu(x @ node_w + node_b), f32 + bf16 out --------
__global__ __launch_bounds__(256) void k_node_enc(const float* __restrict__ x,
                                                  const ushort_t* __restrict__ w0T,
                                                  const float* __restrict__ nb,
                                                  float* __restrict__ h,
                                                  ushort_t* __restrict__ hb) {
    __shared__ __align__(16) short lB[HID * IN_CH];
    for (int c = threadIdx.x; c < HID * IN_CH / 8; c += 256) {
        int row = c >> 3, k0 = (c & 7) * 8;
        short8 v = *(const short8*)(w0T + row * IN_CH + k0);
        int g = (k0 >> 3) ^ (row & 7);
        *(short8*)&lB[row * IN_CH + g * 8] = v;
    }
    __syncthreads();
    int wv = threadIdx.x >> 6, l6 = threadIdx.x & 63;
    int lr = l6 & 15, lg = l6 >> 4;
    int grow = blockIdx.x * 64 + wv * 16 + lr;
    f32x4 acc[8];
#pragma unroll
    for (int nt = 0; nt < 8; ++nt) acc[nt] = (f32x4){0.f, 0.f, 0.f, 0.f};
#pragma unroll
    for (int kt = 0; kt < 2; ++kt) {
        int kk = kt * 32 + lg * 8;
        short8 a = {0, 0, 0, 0, 0, 0, 0, 0};
        if (grow < N_NODES) {
            const float* xr = x + (long)grow * IN_CH + kk;
            f32x4 v0 = *(const f32x4*)xr;
            f32x4 v1 = *(const f32x4*)(xr + 4);
#pragma unroll
            for (int j = 0; j < 4; ++j) { a[j] = (short)f2b(v0[j]); a[4 + j] = (short)f2b(v1[j]); }
        }
#pragma unroll
        for (int nt = 0; nt < 8; ++nt) {
            int brow = nt * 16 + lr;
            short8 b = *(const short8*)&lB[brow * IN_CH + (((kk >> 3) ^ (brow & 7)) << 3)];
            acc[nt] = __builtin_amdgcn_mfma_f32_16x16x32_bf16(a, b, acc[nt], 0, 0, 0);
        }
    }
    int orow0 = blockIdx.x * 64 + wv * 16 + lg * 4;
#pragma unroll
    for (int nt = 0; nt < 8; ++nt) {
        int col = nt * 16 + lr;
        float bias = nb[col];
#pragma unroll
        for (int r = 0; r < 4; ++r) {
            int row = orow0 + r;
            if (row < N_NODES) {
                float v = fmaxf(acc[nt][r] + bias, 0.f);
                h[(long)row * HID + col] = v;
                hb[(long)row * HID + col] = f2b(v);
            }
        }
    }
}

// ---------------- per-layer edge GEMM (chunk [ce0,ce1)) ----------------
__global__ __launch_bounds__(256) void k_edgegemm(const ushort_t* __restrict__ ea_sb,
                                                  const ushort_t* __restrict__ WcbT,
                                                  const float* __restrict__ cc,
                                                  ushort_t* __restrict__ g, int l,
                                                  int ce0, int ce1) {
    int wv = threadIdx.x >> 6, l6 = threadIdx.x & 63;
    int lr = l6 & 15, lg = l6 >> 4;
    short8 af[8];
    f32x4 cv[8];
    const ushort_t* wp = WcbT + (long)l * HID * 32;
#pragma unroll
    for (int nt = 0; nt < 8; ++nt) {
        af[nt] = *(const short8*)(wp + (nt * 16 + lr) * 32 + lg * 8);
        cv[nt] = *(const f32x4*)(cc + l * HID + nt * 16 + lg * 4);
    }
    for (int it = 0; it < 4; ++it) {
        int e0 = ce0 + blockIdx.x * 256 + wv * 64 + it * 16;
        int e = e0 + lr;
        short8 b = {0, 0, 0, 0, 0, 0, 0, 0};
        if (e < ce1 && lg < 2) b = *(const short8*)(ea_sb + (long)e * EDGE_DIM + lg * 8);
        f32x4 acc[8];
#pragma unroll
        for (int nt = 0; nt < 8; ++nt) acc[nt] = (f32x4){0.f, 0.f, 0.f, 0.f};
#pragma unroll
        for (int nt = 0; nt < 8; ++nt)
            acc[nt] = __builtin_amdgcn_mfma_f32_16x16x32_bf16(af[nt], b, acc[nt], 0, 0, 0);
        if (e < ce1) {
            ushort_t* gp = g + (long)(e - ce0) * HID + lg * 4;
#pragma unroll
            for (int nt = 0; nt < 8; ++nt) {
                s16x4 o;
#pragma unroll
                for (int r = 0; r < 4; ++r) o[r] = (short)f2b(acc[nt][r] + cv[nt][r]);
                *(s16x4*)(gp + nt * 16) = o;
            }
        }
    }
}

// ---------------- per-layer aggregation over chunk [ce0,ce1) ----------------
__global__ __launch_bounds__(256) void k_edge2(const ushort_t* __restrict__ g,
                                               const int* __restrict__ src_s,
                                               const int* __restrict__ offs,
                                               const int* __restrict__ deg,
                                               const float* __restrict__ h,
                                               const ushort_t* __restrict__ hb,
                                               const float* __restrict__ epsv,
                                               float* __restrict__ zacc,
                                               ushort_t* __restrict__ z,
                                               int l, int ce0, int ce1, int mode) {
    int lane = threadIdx.x & 63;
    int node = blockIdx.x * 4 + (threadIdx.x >> 6);
    if (node >= N_NODES) return;
    bool first = mode & 1, last = (mode & 2) != 0;
    int ch0 = lane * 2;
    int s0 = offs[node];
    int dg = deg[node];
    int e_lo = max(s0, ce0);
    int e_hi = min(s0 + dg, ce1);
    if (e_lo >= e_hi && !first && !last) return;
    float a0 = 0.f, a1 = 0.f;
    int i = e_lo;
    for (; i + 4 <= e_hi; i += 4) {
        long eg = (long)(i - ce0);
        int sa = src_s[i], sb_ = src_s[i + 1], sc_ = src_s[i + 2], sd_ = src_s[i + 3];
        unsigned ga = *(const unsigned*)(g + eg * HID + ch0);
        unsigned gb = *(const unsigned*)(g + (eg + 1) * HID + ch0);
        unsigned gc = *(const unsigned*)(g + (eg + 2) * HID + ch0);
        unsigned gd = *(const unsigned*)(g + (eg + 3) * HID + ch0);
        unsigned ha = *(const unsigned*)(hb + (long)sa * HID + ch0);
        unsigned hbv = *(const unsigned*)(hb + (long)sb_ * HID + ch0);
        unsigned hc = *(const unsigned*)(hb + (long)sc_ * HID + ch0);
        unsigned hd = *(const unsigned*)(hb + (long)sd_ * HID + ch0);
        a0 += fmaxf(b2f((ushort_t)(ha & 0xffff)) + b2f((ushort_t)(ga & 0xffff)), 0.f);
        a1 += fmaxf(b2f((ushort_t)(ha >> 16)) + b2f((ushort_t)(ga >> 16)), 0.f);
        a0 += fmaxf(b2f((ushort_t)(hbv & 0xffff)) + b2f((ushort_t)(gb & 0xffff)), 0.f);
        a1 += fmaxf(b2f((ushort_t)(hbv >> 16)) + b2f((ushort_t)(gb >> 16)), 0.f);
        a0 += fmaxf(b2f((ushort_t)(hc & 0xffff)) + b2f((ushort_t)(gc & 0xffff)), 0.f);
        a1 += fmaxf(b2f((ushort_t)(hc >> 16)) + b2f((ushort_t)(gc >> 16)), 0.f);
        a0 += fmaxf(b2f((ushort_t)(hd & 0xffff)) + b2f((ushort_t)(gd & 0xffff)), 0.f);
        a1 += fmaxf(b2f((ushort_t)(hd >> 16)) + b2f((ushort_t)(gd >> 16)), 0.f);
    }
    for (; i < e_hi; ++i) {
        long eg = (long)(i - ce0);
        int s = src_s[i];
        unsigned gv = *(const unsigned*)(g + eg * HID + ch0);
        unsigned hv = *(const unsigned*)(hb + (long)s * HID + ch0);
        a0 += fmaxf(b2f((ushort_t)(hv & 0xffff)) + b2f((ushort_t)(gv & 0xffff)), 0.f);
        a1 += fmaxf(b2f((ushort_t)(hv >> 16)) + b2f((ushort_t)(gv >> 16)), 0.f);
    }
    if (!first) {
        f32x2 p = *(const f32x2*)(zacc + (long)node * HID + ch0);
        a0 += p[0]; a1 += p[1];
    }
    if (last) {
        float ep1 = 1.f + epsv[l];
        f32x2 hn = *(const f32x2*)(h + (long)node * HID + ch0);
        unsigned zz = (unsigned)f2b(fmaf(ep1, hn[0], a0)) |
                      ((unsigned)f2b(fmaf(ep1, hn[1], a1)) << 16);
        *(unsigned*)(z + (long)node * HID + ch0) = zz;
    } else {
        *(f32x2*)(zacc + (long)node * HID + ch0) = (f32x2){a0, a1};
    }
}

// ---------------- mlp1: one 64-node tile/block, LDS weight half (A), packed stores ----
__global__ __launch_bounds__(256) void k_mlp1(const ushort_t* __restrict__ z,
                                              const ushort_t* __restrict__ w1T,
                                              const float* __restrict__ b1,
                                              ushort_t* __restrict__ ibuf, int l) {
    __shared__ __align__(16) short lBw[128 * HID];  // 32 KB: 128 feats x K=128
    int half = blockIdx.x & 1;
    int tile = blockIdx.x >> 1;  // [0, MT64)
    const ushort_t* wl = w1T + (long)l * HID2 * HID + (long)half * 128 * HID;
    for (int c = threadIdx.x; c < 128 * HID / 8; c += 256) {
        int row = c >> 4, k0 = (c & 15) * 8;
        short8 v = *(const short8*)(wl + row * HID + k0);
        int gsw = (k0 >> 3) ^ (row & 7);
        *(short8*)&lBw[row * HID + gsw * 8] = v;
    }
    int wv = threadIdx.x >> 6, l6 = threadIdx.x & 63;
    int lr = l6 & 15, lg = l6 >> 4;
    int node = tile * 64 + wv * 16 + lr;
    short8 b[4];
    const ushort_t* zr = z + (long)node * HID;
#pragma unroll
    for (int kt = 0; kt < 4; ++kt) b[kt] = *(const short8*)(zr + kt * 32 + lg * 8);
    __syncthreads();
#pragma unroll
    for (int nt = 0; nt < 8; ++nt) {
        f32x4 acc = (f32x4){0.f, 0.f, 0.f, 0.f};
        int brow = nt * 16 + lr;
#pragma unroll
        for (int kt = 0; kt < 4; ++kt) {
            short8 af = *(const short8*)&lBw[brow * HID + (((kt * 4 + lg) ^ (brow & 7)) << 3)];
            acc = __builtin_amdgcn_mfma_f32_16x16x32_bf16(af, b[kt], acc, 0, 0, 0);
        }
        f32x4 bv = *(const f32x4*)(b1 + l * HID2 + half * 128 + nt * 16 + lg * 4);
        s16x4 o;
#pragma unroll
        for (int r = 0; r < 4; ++r) o[r] = (short)f2b(fmaxf(acc[r] + bv[r], 0.f));
        *(s16x4*)(ibuf + (long)node * HID2 + half * 128 + nt * 16 + lg * 4) = o;
    }
}

// ---------------- mlp2: one 64-node tile/block, LDS weight half (A), BN stats via LDS ----
__global__ __launch_bounds__(256) void k_mlp2(const ushort_t* __restrict__ ibuf,
                                              const ushort_t* __restrict__ w2T,
                                              const float* __restrict__ b2,
                                              ushort_t* __restrict__ z2,
                                              float* __restrict__ bnstats, int l) {
    __shared__ __align__(16) short lBw[64 * HID2];  // 32 KB: 64 feats x K=256
    __shared__ float lStat[2][64];
    int half = blockIdx.x & 1;
    int tile = blockIdx.x >> 1;
    const ushort_t* wl = w2T + (long)l * HID * HID2 + (long)half * 64 * HID2;
    for (int c = threadIdx.x; c < 64 * HID2 / 8; c += 256) {
        int row = c >> 5, k0 = (c & 31) * 8;
        short8 v = *(const short8*)(wl + row * HID2 + k0);
        int gsw = (k0 >> 3) ^ (row & 7);
        *(short8*)&lBw[row * HID2 + gsw * 8] = v;
    }
    if (threadIdx.x < 128) lStat[threadIdx.x >> 6][threadIdx.x & 63] = 0.f;
    int wv = threadIdx.x >> 6, l6 = threadIdx.x & 63;
    int lr = l6 & 15, lg = l6 >> 4;
    int node = tile * 64 + wv * 16 + lr;
    bool valid = node < N_NODES;
    short8 b[8];
    const ushort_t* ir = ibuf + (long)node * HID2;
#pragma unroll
    for (int kt = 0; kt < 8; ++kt) b[kt] = *(const short8*)(ir + kt * 32 + lg * 8);
    __syncthreads();
#pragma unroll
    for (int nt = 0; nt < 4; ++nt) {
        f32x4 acc = (f32x4){0.f, 0.f, 0.f, 0.f};
        int brow = nt * 16 + lr;
#pragma unroll
        for (int kt = 0; kt < 8; ++kt) {
            short8 af = *(const short8*)&lBw[brow * HID2 + (((kt * 4 + lg) ^ (brow & 7)) << 3)];
            acc = __builtin_amdgcn_mfma_f32_16x16x32_bf16(af, b[kt], acc, 0, 0, 0);
        }
        f32x4 bv = *(const f32x4*)(b2 + l * HID + half * 64 + nt * 16 + lg * 4);
        s16x4 o;
#pragma unroll
        for (int r = 0; r < 4; ++r) {
            float v = acc[r] + bv[r];
            o[r] = (short)f2b(v);
            float s = valid ? v : 0.f, q = valid ? v * v : 0.f;
            s += __shfl_xor(s, 1); s += __shfl_xor(s, 2);
            s += __shfl_xor(s, 4); s += __shfl_xor(s, 8);
            q += __shfl_xor(q, 1); q += __shfl_xor(q, 2);
            q += __shfl_xor(q, 4); q += __shfl_xor(q, 8);
            if (lr == 0) {
                int f = nt * 16 + lg * 4 + r;  // feat within half [0,64)
                atomicAdd(&lStat[0][f], s);
                atomicAdd(&lStat[1][f], q);
            }
        }
        *(s16x4*)(z2 + (long)node * HID + half * 64 + nt * 16 + lg * 4) = o;
    }
    __syncthreads();
    if (threadIdx.x < 128) {
        int which = threadIdx.x >> 6, f = threadIdx.x & 63;
        atomicAdd(&bnstats[(which * NLAYER + l) * HID + half * 64 + f], lStat[which][f]);
    }
}

// ---------------- BN apply + residual + relu ----------------
__global__ __launch_bounds__(1024) void k_resid(const ushort_t* __restrict__ z2,
                                                const float* __restrict__ bnstats,
                                                const float* __restrict__ bng,
                                                const float* __restrict__ bnb,
                                                float* __restrict__ h,
                                                ushort_t* __restrict__ hb, int l) {
    long i = (long)blockIdx.x * 1024 + threadIdx.x;
    int c = (int)(i & (HID - 1));
    float inv = 1.f / (float)N_NODES;
    float mu = bnstats[l * HID + c] * inv;
    float var = bnstats[(NLAYER + l) * HID + c] * inv - mu * mu;
    float A = rsqrtf(var + 1e-5f) * bng[l * HID + c];
    float B = bnb[l * HID + c] - mu * A;
    float v = fmaf(b2f(z2[i]), A, B) + h[i];
    v = fmaxf(v, 0.f);
    h[i] = v;
    hb[i] = f2b(v);
}

// ---------------- pooling ----------------
__global__ void k_gstart(const int* __restrict__ batch, int* __restrict__ gstart) {
    int g = threadIdx.x;
    if (g > NGRAPH) return;
    int lo = 0, hi = N_NODES;
    while (lo < hi) { int mid = (lo + hi) >> 1; if (batch[mid] < g) lo = mid + 1; else hi = mid; }
    gstart[g] = lo;
}

__global__ __launch_bounds__(512) void k_pool(const float* __restrict__ h,
                                              const int* __restrict__ gstart,
                                              float* __restrict__ pooled,
                                              float* __restrict__ outp) {
    __shared__ float red[4][HID];
    int g = blockIdx.x;
    int ch = threadIdx.x & 127, seg = threadIdx.x >> 7;
    int st = gstart[g], en = gstart[g + 1];
    float s = 0.f;
    for (int i = st + seg; i < en; i += 4) s += h[(long)i * HID + ch];
    red[seg][ch] = s;
    __syncthreads();
    if (seg == 0) {
        float p = (red[0][ch] + red[1][ch] + red[2][ch] + red[3][ch]) /
                  fmaxf((float)(en - st), 1.f);
        pooled[g * HID + ch] = p;
        outp[g * HID + ch] = p;
    }
}

// ---------------- output MLP ----------------
__global__ __launch_bounds__(128) void k_outmlp(const float* __restrict__ pooled,
                                                const float* __restrict__ w1,
                                                const float* __restrict__ b1,
                                                const float* __restrict__ w2,
                                                const float* __restrict__ b2,
                                                float* __restrict__ outl) {
    __shared__ float pr[HID];
    __shared__ float hid[64];
    int g = blockIdx.x, t = threadIdx.x;
    pr[t] = pooled[g * HID + t];
    __syncthreads();
    if (t < 64) {
        float a = b1[t];
        for (int k = 0; k < HID; ++k) a = fmaf(pr[k], w1[k * 64 + t], a);
        hid[t] = fmaxf(a, 0.f);
    }
    __syncthreads();
    float a = b2[t];
#pragma unroll
    for (int j = 0; j < 64; ++j) a = fmaf(hid[j], w2[j * HID + t], a);
    outl[g * HID + t] = a;
}

// =====================================================================================
extern "C" void kernel_launch(void* const* d_in, const int* in_sizes, int n_in,
                              void* d_out, int out_size, void* d_ws, size_t ws_size,
                              hipStream_t stream) {
    (void)in_sizes; (void)n_in; (void)out_size;
    const float* x      = (const float*)d_in[0];
    const int*   ei     = (const int*)d_in[1];
    const float* ea     = (const float*)d_in[2];
    const int*   batch  = (const int*)d_in[3];
    const float* node_w = (const float*)d_in[4];
    const float* node_b = (const float*)d_in[5];
    const float* edge_w = (const float*)d_in[6];
    const float* edge_b = (const float*)d_in[7];
    const float* epsv   = (const float*)d_in[8];
    const float* lin_w  = (const float*)d_in[9];
    const float* lin_b  = (const float*)d_in[10];
    const float* m1w    = (const float*)d_in[11];
    const float* m1b    = (const float*)d_in[12];
    const float* m2w    = (const float*)d_in[13];
    const float* m2b    = (const float*)d_in[14];
    const float* bng    = (const float*)d_in[15];
    const float* bnb    = (const float*)d_in[16];
    const float* ow1    = (const float*)d_in[17];
    const float* ob1    = (const float*)d_in[18];
    const float* ow2    = (const float*)d_in[19];
    const float* ob2    = (const float*)d_in[20];

    const size_t MiB = 1024ull * 1024ull;
    int NC;
    if      (ws_size >= 275 * MiB) NC = 1;
    else if (ws_size >= 193 * MiB) NC = 2;
    else if (ws_size >= 152 * MiB) NC = 4;
    else                           NC = 8;
    int EC = (N_EDGES + NC - 1) / NC;

    char* ws = (char*)d_ws;
    size_t off = 0;
    auto alloc = [&](size_t bytes) -> char* {
        char* p = ws + off;
        off = (off + bytes + 255) & ~(size_t)255;
        return p;
    };
    float*    h       = (float*)alloc((size_t)NPAD * HID * 4);
    ushort_t* hb      = (ushort_t*)alloc((size_t)NPAD * HID * 2);
    ushort_t* z       = (ushort_t*)alloc((size_t)NPAD * HID * 2);   // reused as z2
    ushort_t* ibuf    = (ushort_t*)alloc((size_t)NPAD * HID2 * 2);  // aliased: zacc, perm
    ushort_t* ea_sb   = (ushort_t*)alloc((size_t)N_EDGES * EDGE_DIM * 2 + 64);
    ushort_t* g       = (ushort_t*)alloc((size_t)EC * HID * 2);
    int*      src_s   = (int*)alloc((size_t)N_EDGES * 4);
    int*      deg     = (int*)alloc((size_t)N_NODES * 4);
    int*      offs    = (int*)alloc((size_t)N_NODES * 4);
    int*      cursor  = (int*)alloc((size_t)N_NODES * 4);
    int*      bsum    = (int*)alloc(64 * 4);
    ushort_t* WcbT    = (ushort_t*)alloc((size_t)NLAYER * HID * 32 * 2);
    float*    cc      = (float*)alloc((size_t)NLAYER * HID * 4);
    ushort_t* w0T     = (ushort_t*)alloc((size_t)HID * IN_CH * 2);
    ushort_t* w1T     = (ushort_t*)alloc((size_t)NLAYER * HID2 * HID * 2);
    ushort_t* w2T     = (ushort_t*)alloc((size_t)NLAYER * HID * HID2 * 2);
    float*    bnstats = (float*)alloc((size_t)2 * NLAYER * HID * 4);
    int*      gstart  = (int*)alloc((NGRAPH + 1) * 4);
    float*    pooled  = (float*)alloc((size_t)NGRAPH * HID * 4);
    float*    zacc    = (float*)ibuf;  // alias: chunked-edge accumulator
    int*      perm    = (int*)ibuf;    // alias: CSR build only
    ushort_t* z2      = z;

    (void)hipMemsetAsync(deg, 0, (size_t)N_NODES * 4, stream);
    (void)hipMemsetAsync(cursor, 0, (size_t)N_NODES * 4, stream);
    (void)hipMemsetAsync(bnstats, 0, (size_t)2 * NLAYER * HID * 4, stream);

    k_transpose_cvt<<<64, 256, 0, stream>>>(node_w, w0T, 1, IN_CH, HID);
    k_transpose_cvt<<<640, 256, 0, stream>>>(m1w, w1T, NLAYER, HID, HID2);
    k_transpose_cvt<<<640, 256, 0, stream>>>(m2w, w2T, NLAYER, HID2, HID);
    k_combine<<<NLAYER, HID, 0, stream>>>(edge_w, edge_b, lin_w, lin_b, WcbT, cc);

    k_hist<<<N_EDGES / 256, 256, 0, stream>>>(ei, deg);
    k_scan1<<<49, 1024, 0, stream>>>(deg, offs, bsum);
    k_scan2<<<1, 1, 0, stream>>>(bsum, 49);
    k_scan3<<<49, 1024, 0, stream>>>(offs, bsum);
    k_scatter1<<<N_EDGES / 256, 256, 0, stream>>>(ei, offs, cursor, perm);
    k_gather<<<N_EDGES / 256, 256, 0, stream>>>(perm, ei, ea, src_s, ea_sb);

    k_node_enc<<<NPAD / 64, 256, 0, stream>>>(x, w0T, node_b, h, hb);

    for (int l = 0; l < NLAYER; ++l) {
        for (int c = 0; c < NC; ++c) {
            int ce0 = c * EC;
            int ce1 = (ce0 + EC < N_EDGES) ? (ce0 + EC) : N_EDGES;
            int nblk = (ce1 - ce0 + 255) / 256;
            int mode = (c == 0 ? 1 : 0) | (c == NC - 1 ? 2 : 0);
            k_edgegemm<<<nblk, 256, 0, stream>>>(ea_sb, WcbT, cc, g, l, ce0, ce1);
            k_edge2<<<(N_NODES + 3) / 4, 256, 0, stream>>>(g, src_s, offs, deg, h, hb,
                                                           epsv, zacc, z, l, ce0, ce1, mode);
        }
        k_mlp1<<<MT64 * 2, 256, 0, stream>>>(z, w1T, m1b, ibuf, l);
        k_mlp2<<<MT64 * 2, 256, 0, stream>>>(ibuf, w2T, m2b, z2, bnstats, l);
        k_resid<<<(N_NODES * HID) / 1024, 1024, 0, stream>>>(z2, bnstats, bng, bnb, h, hb, l);
    }

    k_gstart<<<1, 256, 0, stream>>>(batch, gstart);
    k_pool<<<NGRAPH, 512, 0, stream>>>(h, gstart, pooled, (float*)d_out + NGRAPH * HID);
    k_outmlp<<<NGRAPH, HID, 0, stream>>>(pooled, ow1, ob1, ow2, ob2, (float*)d_out);
}

// Round 16
// 1078.136 us; speedup vs baseline: 1.1098x; 1.0110x over previous
//
#include <hip/hip_runtime.h>

#define N_NODES  50000
#define NPAD     50048
#define N_EDGES  640000
#define IN_CH    64
#define EDGE_DIM 16
#define HID      128
#define HID2     256
#define NLAYER   5
#define NGRAPH   128
#define MT64     (NPAD / 64)

typedef unsigned short ushort_t;
typedef __attribute__((ext_vector_type(8))) short short8;
typedef __attribute__((ext_vector_type(4))) short s16x4;
typedef __attribute__((ext_vector_type(4))) float f32x4;
typedef __attribute__((ext_vector_type(2))) float f32x2;

__device__ __forceinline__ float b2f(ushort_t u) {
    union { unsigned v; float f; } x; x.v = ((unsigned)u) << 16; return x.f;
}
__device__ __forceinline__ ushort_t f2b(float f) {
    union { float f; unsigned u; } x; x.f = f;
    unsigned u = x.u;
    unsigned r = (u + 0x7FFFu + ((u >> 16) & 1u)) >> 16;
    return (ushort_t)r;
}

// ---------------- prep: all three weight transposes in one launch ----------------
__global__ void k_transpose_all(const float* __restrict__ w0,   // [IN_CH][HID]
                                const float* __restrict__ w1,   // [L][HID][HID2]
                                const float* __restrict__ w2,   // [L][HID2][HID]
                                ushort_t* __restrict__ w0T,
                                ushort_t* __restrict__ w1T,
                                ushort_t* __restrict__ w2T) {
    const long n0 = (long)IN_CH * HID;
    const long n1 = (long)NLAYER * HID * HID2;
    const long n2 = (long)NLAYER * HID2 * HID;
    long total = n0 + n1 + n2;
    for (long i = (long)blockIdx.x * blockDim.x + threadIdx.x; i < total;
         i += (long)gridDim.x * blockDim.x) {
        if (i < n0) {
            int k = (int)(i / HID), n = (int)(i - (long)k * HID);
            w0T[(long)n * IN_CH + k] = f2b(w0[i]);
        } else if (i < n0 + n1) {
            long j = i - n0;
            int b = (int)(j / ((long)HID * HID2));
            int rem = (int)(j - (long)b * HID * HID2);
            int k = rem / HID2, n = rem - k * HID2;
            w1T[(long)b * HID * HID2 + (long)n * HID + k] = f2b(w1[j]);
        } else {
            long j = i - n0 - n1;
            int b = (int)(j / ((long)HID2 * HID));
            int rem = (int)(j - (long)b * HID2 * HID);
            int k = rem / HID, n = rem - k * HID;
            w2T[(long)b * HID2 * HID + (long)n * HID2 + k] = f2b(w2[j]);
        }
    }
}

// WcbT bf16 [l][col=128][k=32 zero-padded] + cc f32
__global__ __launch_bounds__(128) void k_combine(const float* __restrict__ ew,
                                                 const float* __restrict__ eb,
                                                 const float* __restrict__ lw,
                                                 const float* __restrict__ lb,
                                                 ushort_t* __restrict__ WcbT,
                                                 float* __restrict__ cc) {
    int l = blockIdx.x, j = threadIdx.x;
    float accW[EDGE_DIM];
#pragma unroll
    for (int k = 0; k < EDGE_DIM; ++k) accW[k] = 0.f;
    float accc = 0.f;
    for (int i = 0; i < HID; ++i) {
        float lwv = lw[((long)l * HID + i) * HID + j];
        accc = fmaf(eb[i], lwv, accc);
#pragma unroll
        for (int k = 0; k < EDGE_DIM; ++k)
            accW[k] = fmaf(ew[k * HID + i], lwv, accW[k]);
    }
    ushort_t* wp = WcbT + ((long)l * HID + j) * 32;
#pragma unroll
    for (int k = 0; k < EDGE_DIM; ++k) wp[k] = f2b(accW[k]);
#pragma unroll
    for (int k = EDGE_DIM; k < 32; ++k) wp[k] = 0;
    cc[l * HID + j] = accc + lb[l * HID + j];
}

// ---------------- CSR build ----------------
__global__ __launch_bounds__(256) void k_hist(const int* __restrict__ ei, int* __restrict__ deg) {
    int e = blockIdx.x * 256 + threadIdx.x;
    if (e < N_EDGES) atomicAdd(&deg[ei[N_EDGES + e]], 1);
}

__global__ __launch_bounds__(1024) void k_scan1(const int* __restrict__ deg,
                                                int* __restrict__ offs, int* __restrict__ bsum) {
    __shared__ int s[1024];
    int i = blockIdx.x * 1024 + threadIdx.x;
    int v = (i < N_NODES) ? deg[i] : 0;
    s[threadIdx.x] = v;
    __syncthreads();
    for (int off = 1; off < 1024; off <<= 1) {
        int t = (threadIdx.x >= off) ? s[threadIdx.x - off] : 0;
        __syncthreads();
        s[threadIdx.x] += t;
        __syncthreads();
    }
    if (i < N_NODES) offs[i] = s[threadIdx.x] - v;  // exclusive
    if (threadIdx.x == 1023) bsum[blockIdx.x] = s[1023];
}

// 64-thread wave inclusive-scan over nb<=64 entries -> exclusive in place
__global__ void k_scan2(int* __restrict__ bsum, int nb) {
    int t = threadIdx.x;
    int v = (t < nb) ? bsum[t] : 0;
    int x = v;
#pragma unroll
    for (int off = 1; off < 64; off <<= 1) {
        int y = __shfl_up(x, off);
        if ((t & 63) >= off) x += y;
    }
    if (t < nb) bsum[t] = x - v;  // exclusive
}

__global__ __launch_bounds__(1024) void k_scan3(int* __restrict__ offs, const int* __restrict__ bsum) {
    int i = blockIdx.x * 1024 + threadIdx.x;
    if (i < N_NODES) offs[i] += bsum[blockIdx.x];
}

// pos computation + 4B perm scatter only
__global__ __launch_bounds__(256) void k_scatter1(const int* __restrict__ ei,
                                                  const int* __restrict__ offs,
                                                  int* __restrict__ cursor,
                                                  int* __restrict__ perm) {
    int e = blockIdx.x * 256 + threadIdx.x;
    if (e >= N_EDGES) return;
    int d = ei[N_EDGES + e];
    int pos = offs[d] + atomicAdd(&cursor[d], 1);
    perm[pos] = e;
}

// gather reads, coalesced writes
__global__ __launch_bounds__(256) void k_gather(const int* __restrict__ perm,
                                                const int* __restrict__ ei,
                                                const float* __restrict__ ea,
                                                int* __restrict__ src_s,
                                                ushort_t* __restrict__ ea_sb) {
    int p = blockIdx.x * 256 + threadIdx.x;
    if (p >= N_EDGES) return;
    int e = perm[p];
    src_s[p] = ei[e];
    const f32x4* srcp = (const f32x4*)(ea + (long)e * EDGE_DIM);
    f32x4 v0 = srcp[0], v1 = srcp[1], v2 = srcp[2], v3 = srcp[3];
    short8 o0, o1;
#pragma unroll
    for (int j = 0; j < 4; ++j) {
        o0[j] = (short)f2b(v0[j]); o0[4 + j] = (short)f2b(v1[j]);
        o1[j] = (short)f2b(v2[j]); o1[4 + j] = (short)f2b(v3[j]);
    }
    short8* dst = (short8*)(ea_sb + (long)p * EDGE_DIM);
    dst[0] = o0;
    dst[1] = o1;
}

// ---------------- node encoder: h = relu(x @ node_w + node_b), f32 + bf16 out --------
__global__ __launch_bounds__(256) void k_node_enc(const float* __restrict__ x,
                                                  const ushort_t* __restrict__ w0T,
                                                  const float* __restrict__ nb,
                                                  float* __restrict__ h,
                                                  ushort_t* __restrict__ hb) {
    __shared__ __align__(16) short lB[HID * IN_CH];
    for (int c = threadIdx.x; c < HID * IN_CH / 8; c += 256) {
        int row = c >> 3, k0 = (c & 7) * 8;
        short8 v = *(const short8*)(w0T + row * IN_CH + k0);
        int g = (k0 >> 3) ^ (row & 7);
        *(short8*)&lB[row * IN_CH + g * 8] = v;
    }
    __syncthreads();
    int wv = threadIdx.x >> 6, l6 = threadIdx.x & 63;
    int lr = l6 & 15, lg = l6 >> 4;
    int grow = blockIdx.x * 64 + wv * 16 + lr;
    f32x4 acc[8];
#pragma unroll
    for (int nt = 0; nt < 8; ++nt) acc[nt] = (f32x4){0.f, 0.f, 0.f, 0.f};
#pragma unroll
    for (int kt = 0; kt < 2; ++kt) {
        int kk = kt * 32 + lg * 8;
        short8 a = {0, 0, 0, 0, 0, 0, 0, 0};
        if (grow < N_NODES) {
            const float* xr = x + (long)grow * IN_CH + kk;
            f32x4 v0 = *(const f32x4*)xr;
            f32x4 v1 = *(const f32x4*)(xr + 4);
#pragma unroll
            for (int j = 0; j < 4; ++j) { a[j] = (short)f2b(v0[j]); a[4 + j] = (short)f2b(v1[j]); }
        }
#pragma unroll
        for (int nt = 0; nt < 8; ++nt) {
            int brow = nt * 16 + lr;
            short8 b = *(const short8*)&lB[brow * IN_CH + (((kk >> 3) ^ (brow & 7)) << 3)];
            acc[nt] = __builtin_amdgcn_mfma_f32_16x16x32_bf16(a, b, acc[nt], 0, 0, 0);
        }
    }
    int orow0 = blockIdx.x * 64 + wv * 16 + lg * 4;
#pragma unroll
    for (int nt = 0; nt < 8; ++nt) {
        int col = nt * 16 + lr;
        float bias = nb[col];
#pragma unroll
        for (int r = 0; r < 4; ++r) {
            int row = orow0 + r;
            if (row < N_NODES) {
                float v = fmaxf(acc[nt][r] + bias, 0.f);
                h[(long)row * HID + col] = v;
                hb[(long)row * HID + col] = f2b(v);
            }
        }
    }
}

// ---------------- per-layer edge GEMM (chunk [ce0,ce1)) ----------------
__global__ __launch_bounds__(256) void k_edgegemm(const ushort_t* __restrict__ ea_sb,
                                                  const ushort_t* __restrict__ WcbT,
                                                  const float* __restrict__ cc,
                                                  ushort_t* __restrict__ g, int l,
                                                  int ce0, int ce1) {
    int wv = threadIdx.x >> 6, l6 = threadIdx.x & 63;
    int lr = l6 & 15, lg = l6 >> 4;
    short8 af[8];
    f32x4 cv[8];
    const ushort_t* wp = WcbT + (long)l * HID * 32;
#pragma unroll
    for (int nt = 0; nt < 8; ++nt) {
        af[nt] = *(const short8*)(wp + (nt * 16 + lr) * 32 + lg * 8);
        cv[nt] = *(const f32x4*)(cc + l * HID + nt * 16 + lg * 4);
    }
    for (int it = 0; it < 4; ++it) {
        int e0 = ce0 + blockIdx.x * 256 + wv * 64 + it * 16;
        int e = e0 + lr;
        short8 b = {0, 0, 0, 0, 0, 0, 0, 0};
        if (e < ce1 && lg < 2) b = *(const short8*)(ea_sb + (long)e * EDGE_DIM + lg * 8);
        f32x4 acc[8];
#pragma unroll
        for (int nt = 0; nt < 8; ++nt) acc[nt] = (f32x4){0.f, 0.f, 0.f, 0.f};
#pragma unroll
        for (int nt = 0; nt < 8; ++nt)
            acc[nt] = __builtin_amdgcn_mfma_f32_16x16x32_bf16(af[nt], b, acc[nt], 0, 0, 0);
        if (e < ce1) {
            ushort_t* gp = g + (long)(e - ce0) * HID + lg * 4;
#pragma unroll
            for (int nt = 0; nt < 8; ++nt) {
                s16x4 o;
#pragma unroll
                for (int r = 0; r < 4; ++r) o[r] = (short)f2b(acc[nt][r] + cv[nt][r]);
                *(s16x4*)(gp + nt * 16) = o;
            }
        }
    }
}

// ---------------- per-layer aggregation over chunk [ce0,ce1), 8 nodes/block --------
__global__ __launch_bounds__(512) void k_edge2(const ushort_t* __restrict__ g,
                                               const int* __restrict__ src_s,
                                               const int* __restrict__ offs,
                                               const int* __restrict__ deg,
                                               const float* __restrict__ h,
                                               const ushort_t* __restrict__ hb,
                                               const float* __restrict__ epsv,
                                               float* __restrict__ zacc,
                                               ushort_t* __restrict__ z,
                                               int l, int ce0, int ce1, int mode) {
    int lane = threadIdx.x & 63;
    int node = blockIdx.x * 8 + (threadIdx.x >> 6);
    if (node >= N_NODES) return;
    bool first = mode & 1, last = (mode & 2) != 0;
    int ch0 = lane * 2;
    int s0 = offs[node];
    int dg = deg[node];
    int e_lo = max(s0, ce0);
    int e_hi = min(s0 + dg, ce1);
    if (e_lo >= e_hi && !first && !last) return;
    float a0 = 0.f, a1 = 0.f;
    int i = e_lo;
    for (; i + 4 <= e_hi; i += 4) {
        long eg = (long)(i - ce0);
        int sa = src_s[i], sb_ = src_s[i + 1], sc_ = src_s[i + 2], sd_ = src_s[i + 3];
        unsigned ga = *(const unsigned*)(g + eg * HID + ch0);
        unsigned gb = *(const unsigned*)(g + (eg + 1) * HID + ch0);
        unsigned gc = *(const unsigned*)(g + (eg + 2) * HID + ch0);
        unsigned gd = *(const unsigned*)(g + (eg + 3) * HID + ch0);
        unsigned ha = *(const unsigned*)(hb + (long)sa * HID + ch0);
        unsigned hbv = *(const unsigned*)(hb + (long)sb_ * HID + ch0);
        unsigned hc = *(const unsigned*)(hb + (long)sc_ * HID + ch0);
        unsigned hd = *(const unsigned*)(hb + (long)sd_ * HID + ch0);
        a0 += fmaxf(b2f((ushort_t)(ha & 0xffff)) + b2f((ushort_t)(ga & 0xffff)), 0.f);
        a1 += fmaxf(b2f((ushort_t)(ha >> 16)) + b2f((ushort_t)(ga >> 16)), 0.f);
        a0 += fmaxf(b2f((ushort_t)(hbv & 0xffff)) + b2f((ushort_t)(gb & 0xffff)), 0.f);
        a1 += fmaxf(b2f((ushort_t)(hbv >> 16)) + b2f((ushort_t)(gb >> 16)), 0.f);
        a0 += fmaxf(b2f((ushort_t)(hc & 0xffff)) + b2f((ushort_t)(gc & 0xffff)), 0.f);
        a1 += fmaxf(b2f((ushort_t)(hc >> 16)) + b2f((ushort_t)(gc >> 16)), 0.f);
        a0 += fmaxf(b2f((ushort_t)(hd & 0xffff)) + b2f((ushort_t)(gd & 0xffff)), 0.f);
        a1 += fmaxf(b2f((ushort_t)(hd >> 16)) + b2f((ushort_t)(gd >> 16)), 0.f);
    }
    for (; i < e_hi; ++i) {
        long eg = (long)(i - ce0);
        int s = src_s[i];
        unsigned gv = *(const unsigned*)(g + eg * HID + ch0);
        unsigned hv = *(const unsigned*)(hb + (long)s * HID + ch0);
        a0 += fmaxf(b2f((ushort_t)(hv & 0xffff)) + b2f((ushort_t)(gv & 0xffff)), 0.f);
        a1 += fmaxf(b2f((ushort_t)(hv >> 16)) + b2f((ushort_t)(gv >> 16)), 0.f);
    }
    if (!first) {
        f32x2 p = *(const f32x2*)(zacc + (long)node * HID + ch0);
        a0 += p[0]; a1 += p[1];
    }
    if (last) {
        float ep1 = 1.f + epsv[l];
        f32x2 hn = *(const f32x2*)(h + (long)node * HID + ch0);
        unsigned zz = (unsigned)f2b(fmaf(ep1, hn[0], a0)) |
                      ((unsigned)f2b(fmaf(ep1, hn[1], a1)) << 16);
        *(unsigned*)(z + (long)node * HID + ch0) = zz;
    } else {
        *(f32x2*)(zacc + (long)node * HID + ch0) = (f32x2){a0, a1};
    }
}

// ---------------- mlp1: one 64-node tile/block, LDS weight half (A), packed stores ----
__global__ __launch_bounds__(256) void k_mlp1(const ushort_t* __restrict__ z,
                                              const ushort_t* __restrict__ w1T,
                                              const float* __restrict__ b1,
                                              ushort_t* __restrict__ ibuf, int l) {
    __shared__ __align__(16) short lBw[128 * HID];  // 32 KB: 128 feats x K=128
    int half = blockIdx.x & 1;
    int tile = blockIdx.x >> 1;  // [0, MT64)
    const ushort_t* wl = w1T + (long)l * HID2 * HID + (long)half * 128 * HID;
    for (int c = threadIdx.x; c < 128 * HID / 8; c += 256) {
        int row = c >> 4, k0 = (c & 15) * 8;
        short8 v = *(const short8*)(wl + row * HID + k0);
        int gsw = (k0 >> 3) ^ (row & 7);
        *(short8*)&lBw[row * HID + gsw * 8] = v;
    }
    int wv = threadIdx.x >> 6, l6 = threadIdx.x & 63;
    int lr = l6 & 15, lg = l6 >> 4;
    int node = tile * 64 + wv * 16 + lr;
    short8 b[4];
    const ushort_t* zr = z + (long)node * HID;
#pragma unroll
    for (int kt = 0; kt < 4; ++kt) b[kt] = *(const short8*)(zr + kt * 32 + lg * 8);
    __syncthreads();
#pragma unroll
    for (int nt = 0; nt < 8; ++nt) {
        f32x4 acc = (f32x4){0.f, 0.f, 0.f, 0.f};
        int brow = nt * 16 + lr;
#pragma unroll
        for (int kt = 0; kt < 4; ++kt) {
            short8 af = *(const short8*)&lBw[brow * HID + (((kt * 4 + lg) ^ (brow & 7)) << 3)];
            acc = __builtin_amdgcn_mfma_f32_16x16x32_bf16(af, b[kt], acc, 0, 0, 0);
        }
        f32x4 bv = *(const f32x4*)(b1 + l * HID2 + half * 128 + nt * 16 + lg * 4);
        s16x4 o;
#pragma unroll
        for (int r = 0; r < 4; ++r) o[r] = (short)f2b(fmaxf(acc[r] + bv[r], 0.f));
        *(s16x4*)(ibuf + (long)node * HID2 + half * 128 + nt * 16 + lg * 4) = o;
    }
}

// ---------------- mlp2: one 64-node tile/block, LDS weight half (A), BN stats via LDS ----
__global__ __launch_bounds__(256) void k_mlp2(const ushort_t* __restrict__ ibuf,
                                              const ushort_t* __restrict__ w2T,
                                              const float* __restrict__ b2,
                                              ushort_t* __restrict__ z2,
                                              float* __restrict__ bnstats, int l) {
    __shared__ __align__(16) short lBw[64 * HID2];  // 32 KB: 64 feats x K=256
    __shared__ float lStat[2][64];
    int half = blockIdx.x & 1;
    int tile = blockIdx.x >> 1;
    const ushort_t* wl = w2T + (long)l * HID * HID2 + (long)half * 64 * HID2;
    for (int c = threadIdx.x; c < 64 * HID2 / 8; c += 256) {
        int row = c >> 5, k0 = (c & 31) * 8;
        short8 v = *(const short8*)(wl + row * HID2 + k0);
        int gsw = (k0 >> 3) ^ (row & 7);
        *(short8*)&lBw[row * HID2 + gsw * 8] = v;
    }
    if (threadIdx.x < 128) lStat[threadIdx.x >> 6][threadIdx.x & 63] = 0.f;
    int wv = threadIdx.x >> 6, l6 = threadIdx.x & 63;
    int lr = l6 & 15, lg = l6 >> 4;
    int node = tile * 64 + wv * 16 + lr;
    bool valid = node < N_NODES;
    short8 b[8];
    const ushort_t* ir = ibuf + (long)node * HID2;
#pragma unroll
    for (int kt = 0; kt < 8; ++kt) b[kt] = *(const short8*)(ir + kt * 32 + lg * 8);
    __syncthreads();
#pragma unroll
    for (int nt = 0; nt < 4; ++nt) {
        f32x4 acc = (f32x4){0.f, 0.f, 0.f, 0.f};
        int brow = nt * 16 + lr;
#pragma unroll
        for (int kt = 0; kt < 8; ++kt) {
            short8 af = *(const short8*)&lBw[brow * HID2 + (((kt * 4 + lg) ^ (brow & 7)) << 3)];
            acc = __builtin_amdgcn_mfma_f32_16x16x32_bf16(af, b[kt], acc, 0, 0, 0);
        }
        f32x4 bv = *(const f32x4*)(b2 + l * HID + half * 64 + nt * 16 + lg * 4);
        s16x4 o;
#pragma unroll
        for (int r = 0; r < 4; ++r) {
            float v = acc[r] + bv[r];
            o[r] = (short)f2b(v);
            float s = valid ? v : 0.f, q = valid ? v * v : 0.f;
            s += __shfl_xor(s, 1); s += __shfl_xor(s, 2);
            s += __shfl_xor(s, 4); s += __shfl_xor(s, 8);
            q += __shfl_xor(q, 1); q += __shfl_xor(q, 2);
            q += __shfl_xor(q, 4); q += __shfl_xor(q, 8);
            if (lr == 0) {
                int f = nt * 16 + lg * 4 + r;  // feat within half [0,64)
                atomicAdd(&lStat[0][f], s);
                atomicAdd(&lStat[1][f], q);
            }
        }
        *(s16x4*)(z2 + (long)node * HID + half * 64 + nt * 16 + lg * 4) = o;
    }
    __syncthreads();
    if (threadIdx.x < 128) {
        int which = threadIdx.x >> 6, f = threadIdx.x & 63;
        atomicAdd(&bnstats[(which * NLAYER + l) * HID + half * 64 + f], lStat[which][f]);
    }
}

// ---------------- BN apply + residual + relu ----------------
__global__ __launch_bounds__(1024) void k_resid(const ushort_t* __restrict__ z2,
                                                const float* __restrict__ bnstats,
                                                const float* __restrict__ bng,
                                                const float* __restrict__ bnb,
                                                float* __restrict__ h,
                                                ushort_t* __restrict__ hb, int l) {
    long i = (long)blockIdx.x * 1024 + threadIdx.x;
    int c = (int)(i & (HID - 1));
    float inv = 1.f / (float)N_NODES;
    float mu = bnstats[l * HID + c] * inv;
    float var = bnstats[(NLAYER + l) * HID + c] * inv - mu * mu;
    float A = rsqrtf(var + 1e-5f) * bng[l * HID + c];
    float B = bnb[l * HID + c] - mu * A;
    float v = fmaf(b2f(z2[i]), A, B) + h[i];
    v = fmaxf(v, 0.f);
    h[i] = v;
    hb[i] = f2b(v);
}

// ---------------- pooling (per-block binary search for segment bounds) --------------
__global__ __launch_bounds__(512) void k_pool(const float* __restrict__ h,
                                              const int* __restrict__ batch,
                                              float* __restrict__ pooled,
                                              float* __restrict__ outp) {
    __shared__ float red[4][HID];
    __shared__ int sb[2];
    int g = blockIdx.x;
    if (threadIdx.x < 2) {
        int target = g + threadIdx.x;
        int lo = 0, hi = N_NODES;
        while (lo < hi) { int mid = (lo + hi) >> 1; if (batch[mid] < target) lo = mid + 1; else hi = mid; }
        sb[threadIdx.x] = lo;
    }
    __syncthreads();
    int st = sb[0], en = sb[1];
    int ch = threadIdx.x & 127, seg = threadIdx.x >> 7;
    float s = 0.f;
    for (int i = st + seg; i < en; i += 4) s += h[(long)i * HID + ch];
    red[seg][ch] = s;
    __syncthreads();
    if (seg == 0) {
        float p = (red[0][ch] + red[1][ch] + red[2][ch] + red[3][ch]) /
                  fmaxf((float)(en - st), 1.f);
        pooled[g * HID + ch] = p;
        outp[g * HID + ch] = p;
    }
}

// ---------------- output MLP ----------------
__global__ __launch_bounds__(128) void k_outmlp(const float* __restrict__ pooled,
                                                const float* __restrict__ w1,
                                                const float* __restrict__ b1,
                                                const float* __restrict__ w2,
                                                const float* __restrict__ b2,
                                                float* __restrict__ outl) {
    __shared__ float pr[HID];
    __shared__ float hid[64];
    int g = blockIdx.x, t = threadIdx.x;
    pr[t] = pooled[g * HID + t];
    __syncthreads();
    if (t < 64) {
        float a = b1[t];
        for (int k = 0; k < HID; ++k) a = fmaf(pr[k], w1[k * 64 + t], a);
        hid[t] = fmaxf(a, 0.f);
    }
    __syncthreads();
    float a = b2[t];
#pragma unroll
    for (int j = 0; j < 64; ++j) a = fmaf(hid[j], w2[j * HID + t], a);
    outl[g * HID + t] = a;
}

// =====================================================================================
extern "C" void kernel_launch(void* const* d_in, const int* in_sizes, int n_in,
                              void* d_out, int out_size, void* d_ws, size_t ws_size,
                              hipStream_t stream) {
    (void)in_sizes; (void)n_in; (void)out_size;
    const float* x      = (const float*)d_in[0];
    const int*   ei     = (const int*)d_in[1];
    const float* ea     = (const float*)d_in[2];
    const int*   batch  = (const int*)d_in[3];
    const float* node_w = (const float*)d_in[4];
    const float* node_b = (const float*)d_in[5];
    const float* edge_w = (const float*)d_in[6];
    const float* edge_b = (const float*)d_in[7];
    const float* epsv   = (const float*)d_in[8];
    const float* lin_w  = (const float*)d_in[9];
    const float* lin_b  = (const float*)d_in[10];
    const float* m1w    = (const float*)d_in[11];
    const float* m1b    = (const float*)d_in[12];
    const float* m2w    = (const float*)d_in[13];
    const float* m2b    = (const float*)d_in[14];
    const float* bng    = (const float*)d_in[15];
    const float* bnb    = (const float*)d_in[16];
    const float* ow1    = (const float*)d_in[17];
    const float* ob1    = (const float*)d_in[18];
    const float* ow2    = (const float*)d_in[19];
    const float* ob2    = (const float*)d_in[20];

    const size_t MiB = 1024ull * 1024ull;
    int NC;
    if      (ws_size >= 275 * MiB) NC = 1;
    else if (ws_size >= 193 * MiB) NC = 2;
    else if (ws_size >= 152 * MiB) NC = 4;
    else                           NC = 8;
    int EC = (N_EDGES + NC - 1) / NC;

    char* ws = (char*)d_ws;
    size_t off = 0;
    auto alloc = [&](size_t bytes) -> char* {
        char* p = ws + off;
        off = (off + bytes + 255) & ~(size_t)255;
        return p;
    };
    float*    h       = (float*)alloc((size_t)NPAD * HID * 4);
    ushort_t* hb      = (ushort_t*)alloc((size_t)NPAD * HID * 2);
    ushort_t* z       = (ushort_t*)alloc((size_t)NPAD * HID * 2);   // reused as z2
    ushort_t* ibuf    = (ushort_t*)alloc((size_t)NPAD * HID2 * 2);  // aliased: zacc, perm
    ushort_t* ea_sb   = (ushort_t*)alloc((size_t)N_EDGES * EDGE_DIM * 2 + 64);
    ushort_t* g       = (ushort_t*)alloc((size_t)EC * HID * 2);
    int*      src_s   = (int*)alloc((size_t)N_EDGES * 4);
    int*      deg     = (int*)alloc((size_t)N_NODES * 4);
    int*      offs    = (int*)alloc((size_t)N_NODES * 4);
    int*      cursor  = (int*)alloc((size_t)N_NODES * 4);
    int*      bsum    = (int*)alloc(64 * 4);
    ushort_t* WcbT    = (ushort_t*)alloc((size_t)NLAYER * HID * 32 * 2);
    float*    cc      = (float*)alloc((size_t)NLAYER * HID * 4);
    ushort_t* w0T     = (ushort_t*)alloc((size_t)HID * IN_CH * 2);
    ushort_t* w1T     = (ushort_t*)alloc((size_t)NLAYER * HID2 * HID * 2);
    ushort_t* w2T     = (ushort_t*)alloc((size_t)NLAYER * HID * HID2 * 2);
    float*    bnstats = (float*)alloc((size_t)2 * NLAYER * HID * 4);
    float*    pooled  = (float*)alloc((size_t)NGRAPH * HID * 4);
    float*    zacc    = (float*)ibuf;  // alias: chunked-edge accumulator
    int*      perm    = (int*)ibuf;    // alias: CSR build only
    ushort_t* z2      = z;

    (void)hipMemsetAsync(deg, 0, (size_t)N_NODES * 4, stream);
    (void)hipMemsetAsync(cursor, 0, (size_t)N_NODES * 4, stream);
    (void)hipMemsetAsync(bnstats, 0, (size_t)2 * NLAYER * HID * 4, stream);

    k_transpose_all<<<1280, 256, 0, stream>>>(node_w, m1w, m2w, w0T, w1T, w2T);
    k_combine<<<NLAYER, HID, 0, stream>>>(edge_w, edge_b, lin_w, lin_b, WcbT, cc);

    k_hist<<<N_EDGES / 256, 256, 0, stream>>>(ei, deg);
    k_scan1<<<49, 1024, 0, stream>>>(deg, offs, bsum);
    k_scan2<<<1, 64, 0, stream>>>(bsum, 49);
    k_scan3<<<49, 1024, 0, stream>>>(offs, bsum);
    k_scatter1<<<N_EDGES / 256, 256, 0, stream>>>(ei, offs, cursor, perm);
    k_gather<<<N_EDGES / 256, 256, 0, stream>>>(perm, ei, ea, src_s, ea_sb);

    k_node_enc<<<NPAD / 64, 256, 0, stream>>>(x, w0T, node_b, h, hb);

    for (int l = 0; l < NLAYER; ++l) {
        for (int c = 0; c < NC; ++c) {
            int ce0 = c * EC;
            int ce1 = (ce0 + EC < N_EDGES) ? (ce0 + EC) : N_EDGES;
            int nblk = (ce1 - ce0 + 255) / 256;
            int mode = (c == 0 ? 1 : 0) | (c == NC - 1 ? 2 : 0);
            k_edgegemm<<<nblk, 256, 0, stream>>>(ea_sb, WcbT, cc, g, l, ce0, ce1);
            k_edge2<<<(N_NODES + 7) / 8, 512, 0, stream>>>(g, src_s, offs, deg, h, hb,
                                                           epsv, zacc, z, l, ce0, ce1, mode);
        }
        k_mlp1<<<MT64 * 2, 256, 0, stream>>>(z, w1T, m1b, ibuf, l);
        k_mlp2<<<MT64 * 2, 256, 0, stream>>>(ibuf, w2T, m2b, z2, bnstats, l);
        k_resid<<<(N_NODES * HID) / 1024, 1024, 0, stream>>>(z2, bnstats, bng, bnb, h, hb, l);
    }

    k_pool<<<NGRAPH, 512, 0, stream>>>(h, batch, pooled, (float*)d_out + NGRAPH * HID);
    k_outmlp<<<NGRAPH, HID, 0, stream>>>(pooled, ow1, ob1, ow2, ob2, (float*)d_out);
}

// Round 17
// 1076.576 us; speedup vs baseline: 1.1115x; 1.0014x over previous
//
#include <hip/hip_runtime.h>

#define N_NODES  50000
#define NPAD     50048
#define N_EDGES  640000
#define IN_CH    64
#define EDGE_DIM 16
#define HID      128
#define HID2     256
#define NLAYER   5
#define NGRAPH   128
#define MT64     (NPAD / 64)

typedef unsigned short ushort_t;
typedef __attribute__((ext_vector_type(8))) short short8;
typedef __attribute__((ext_vector_type(4))) short s16x4;
typedef __attribute__((ext_vector_type(4))) float f32x4;
typedef __attribute__((ext_vector_type(2))) float f32x2;
typedef __attribute__((ext_vector_type(4))) int i32x4;

__device__ __forceinline__ float b2f(ushort_t u) {
    union { unsigned v; float f; } x; x.v = ((unsigned)u) << 16; return x.f;
}
__device__ __forceinline__ ushort_t f2b(float f) {
    union { float f; unsigned u; } x; x.f = f;
    unsigned u = x.u;
    unsigned r = (u + 0x7FFFu + ((u >> 16) & 1u)) >> 16;
    return (ushort_t)r;
}

// ---------------- prep: all three weight transposes in one launch ----------------
__global__ void k_transpose_all(const float* __restrict__ w0,   // [IN_CH][HID]
                                const float* __restrict__ w1,   // [L][HID][HID2]
                                const float* __restrict__ w2,   // [L][HID2][HID]
                                ushort_t* __restrict__ w0T,
                                ushort_t* __restrict__ w1T,
                                ushort_t* __restrict__ w2T) {
    const long n0 = (long)IN_CH * HID;
    const long n1 = (long)NLAYER * HID * HID2;
    const long n2 = (long)NLAYER * HID2 * HID;
    long total = n0 + n1 + n2;
    for (long i = (long)blockIdx.x * blockDim.x + threadIdx.x; i < total;
         i += (long)gridDim.x * blockDim.x) {
        if (i < n0) {
            int k = (int)(i / HID), n = (int)(i - (long)k * HID);
            w0T[(long)n * IN_CH + k] = f2b(w0[i]);
        } else if (i < n0 + n1) {
            long j = i - n0;
            int b = (int)(j / ((long)HID * HID2));
            int rem = (int)(j - (long)b * HID * HID2);
            int k = rem / HID2, n = rem - k * HID2;
            w1T[(long)b * HID * HID2 + (long)n * HID + k] = f2b(w1[j]);
        } else {
            long j = i - n0 - n1;
            int b = (int)(j / ((long)HID2 * HID));
            int rem = (int)(j - (long)b * HID2 * HID);
            int k = rem / HID, n = rem - k * HID;
            w2T[(long)b * HID2 * HID + (long)n * HID2 + k] = f2b(w2[j]);
        }
    }
}

// WcbT bf16 [l][col=128][k=32 zero-padded] + cc f32
__global__ __launch_bounds__(128) void k_combine(const float* __restrict__ ew,
                                                 const float* __restrict__ eb,
                                                 const float* __restrict__ lw,
                                                 const float* __restrict__ lb,
                                                 ushort_t* __restrict__ WcbT,
                                                 float* __restrict__ cc) {
    int l = blockIdx.x, j = threadIdx.x;
    float accW[EDGE_DIM];
#pragma unroll
    for (int k = 0; k < EDGE_DIM; ++k) accW[k] = 0.f;
    float accc = 0.f;
    for (int i = 0; i < HID; ++i) {
        float lwv = lw[((long)l * HID + i) * HID + j];
        accc = fmaf(eb[i], lwv, accc);
#pragma unroll
        for (int k = 0; k < EDGE_DIM; ++k)
            accW[k] = fmaf(ew[k * HID + i], lwv, accW[k]);
    }
    ushort_t* wp = WcbT + ((long)l * HID + j) * 32;
#pragma unroll
    for (int k = 0; k < EDGE_DIM; ++k) wp[k] = f2b(accW[k]);
#pragma unroll
    for (int k = EDGE_DIM; k < 32; ++k) wp[k] = 0;
    cc[l * HID + j] = accc + lb[l * HID + j];
}

// ---------------- CSR build (4 edges/thread: 4 atomics in flight) ----------------
__global__ __launch_bounds__(256) void k_hist(const int* __restrict__ ei, int* __restrict__ deg) {
    int e0 = (blockIdx.x * 256 + threadIdx.x) * 4;
    if (e0 >= N_EDGES) return;
    i32x4 d = *(const i32x4*)(ei + N_EDGES + e0);
    atomicAdd(&deg[d.x], 1);
    atomicAdd(&deg[d.y], 1);
    atomicAdd(&deg[d.z], 1);
    atomicAdd(&deg[d.w], 1);
}

__global__ __launch_bounds__(1024) void k_scan1(const int* __restrict__ deg,
                                                int* __restrict__ offs, int* __restrict__ bsum) {
    __shared__ int s[1024];
    int i = blockIdx.x * 1024 + threadIdx.x;
    int v = (i < N_NODES) ? deg[i] : 0;
    s[threadIdx.x] = v;
    __syncthreads();
    for (int off = 1; off < 1024; off <<= 1) {
        int t = (threadIdx.x >= off) ? s[threadIdx.x - off] : 0;
        __syncthreads();
        s[threadIdx.x] += t;
        __syncthreads();
    }
    if (i < N_NODES) offs[i] = s[threadIdx.x] - v;  // exclusive
    if (threadIdx.x == 1023) bsum[blockIdx.x] = s[1023];
}

// 64-thread wave inclusive-scan over nb<=64 entries -> exclusive in place
__global__ void k_scan2(int* __restrict__ bsum, int nb) {
    int t = threadIdx.x;
    int v = (t < nb) ? bsum[t] : 0;
    int x = v;
#pragma unroll
    for (int off = 1; off < 64; off <<= 1) {
        int y = __shfl_up(x, off);
        if ((t & 63) >= off) x += y;
    }
    if (t < nb) bsum[t] = x - v;  // exclusive
}

__global__ __launch_bounds__(1024) void k_scan3(int* __restrict__ offs, const int* __restrict__ bsum) {
    int i = blockIdx.x * 1024 + threadIdx.x;
    if (i < N_NODES) offs[i] += bsum[blockIdx.x];
}

// pos computation + 4B perm scatter, 4 edges/thread (4 atomics+stores in flight)
__global__ __launch_bounds__(256) void k_scatter1(const int* __restrict__ ei,
                                                  const int* __restrict__ offs,
                                                  int* __restrict__ cursor,
                                                  int* __restrict__ perm) {
    int e0 = (blockIdx.x * 256 + threadIdx.x) * 4;
    if (e0 >= N_EDGES) return;
    i32x4 d = *(const i32x4*)(ei + N_EDGES + e0);
    int p0 = offs[d.x] + atomicAdd(&cursor[d.x], 1);
    int p1 = offs[d.y] + atomicAdd(&cursor[d.y], 1);
    int p2 = offs[d.z] + atomicAdd(&cursor[d.z], 1);
    int p3 = offs[d.w] + atomicAdd(&cursor[d.w], 1);
    perm[p0] = e0;
    perm[p1] = e0 + 1;
    perm[p2] = e0 + 2;
    perm[p3] = e0 + 3;
}

// gather reads, coalesced writes
__global__ __launch_bounds__(256) void k_gather(const int* __restrict__ perm,
                                                const int* __restrict__ ei,
                                                const float* __restrict__ ea,
                                                int* __restrict__ src_s,
                                                ushort_t* __restrict__ ea_sb) {
    int p = blockIdx.x * 256 + threadIdx.x;
    if (p >= N_EDGES) return;
    int e = perm[p];
    src_s[p] = ei[e];
    const f32x4* srcp = (const f32x4*)(ea + (long)e * EDGE_DIM);
    f32x4 v0 = srcp[0], v1 = srcp[1], v2 = srcp[2], v3 = srcp[3];
    short8 o0, o1;
#pragma unroll
    for (int j = 0; j < 4; ++j) {
        o0[j] = (short)f2b(v0[j]); o0[4 + j] = (short)f2b(v1[j]);
        o1[j] = (short)f2b(v2[j]); o1[4 + j] = (short)f2b(v3[j]);
    }
    short8* dst = (short8*)(ea_sb + (long)p * EDGE_DIM);
    dst[0] = o0;
    dst[1] = o1;
}

// ---------------- node encoder: h = relu(x @ node_w + node_b), f32 + bf16 out --------
__global__ __launch_bounds__(256) void k_node_enc(const float* __restrict__ x,
                                                  const ushort_t* __restrict__ w0T,
                                                  const float* __restrict__ nb,
                                                  float* __restrict__ h,
                                                  ushort_t* __restrict__ hb) {
    __shared__ __align__(16) short lB[HID * IN_CH];
    for (int c = threadIdx.x; c < HID * IN_CH / 8; c += 256) {
        int row = c >> 3, k0 = (c & 7) * 8;
        short8 v = *(const short8*)(w0T + row * IN_CH + k0);
        int g = (k0 >> 3) ^ (row & 7);
        *(short8*)&lB[row * IN_CH + g * 8] = v;
    }
    __syncthreads();
    int wv = threadIdx.x >> 6, l6 = threadIdx.x & 63;
    int lr = l6 & 15, lg = l6 >> 4;
    int grow = blockIdx.x * 64 + wv * 16 + lr;
    f32x4 acc[8];
#pragma unroll
    for (int nt = 0; nt < 8; ++nt) acc[nt] = (f32x4){0.f, 0.f, 0.f, 0.f};
#pragma unroll
    for (int kt = 0; kt < 2; ++kt) {
        int kk = kt * 32 + lg * 8;
        short8 a = {0, 0, 0, 0, 0, 0, 0, 0};
        if (grow < N_NODES) {
            const float* xr = x + (long)grow * IN_CH + kk;
            f32x4 v0 = *(const f32x4*)xr;
            f32x4 v1 = *(const f32x4*)(xr + 4);
#pragma unroll
            for (int j = 0; j < 4; ++j) { a[j] = (short)f2b(v0[j]); a[4 + j] = (short)f2b(v1[j]); }
        }
#pragma unroll
        for (int nt = 0; nt < 8; ++nt) {
            int brow = nt * 16 + lr;
            short8 b = *(const short8*)&lB[brow * IN_CH + (((kk >> 3) ^ (brow & 7)) << 3)];
            acc[nt] = __builtin_amdgcn_mfma_f32_16x16x32_bf16(a, b, acc[nt], 0, 0, 0);
        }
    }
    int orow0 = blockIdx.x * 64 + wv * 16 + lg * 4;
#pragma unroll
    for (int nt = 0; nt < 8; ++nt) {
        int col = nt * 16 + lr;
        float bias = nb[col];
#pragma unroll
        for (int r = 0; r < 4; ++r) {
            int row = orow0 + r;
            if (row < N_NODES) {
                float v = fmaxf(acc[nt][r] + bias, 0.f);
                h[(long)row * HID + col] = v;
                hb[(long)row * HID + col] = f2b(v);
            }
        }
    }
}

// ---------------- per-layer edge GEMM (chunk [ce0,ce1)) ----------------
__global__ __launch_bounds__(256) void k_edgegemm(const ushort_t* __restrict__ ea_sb,
                                                  const ushort_t* __restrict__ WcbT,
                                                  const float* __restrict__ cc,
                                                  ushort_t* __restrict__ g, int l,
                                                  int ce0, int ce1) {
    int wv = threadIdx.x >> 6, l6 = threadIdx.x & 63;
    int lr = l6 & 15, lg = l6 >> 4;
    short8 af[8];
    f32x4 cv[8];
    const ushort_t* wp = WcbT + (long)l * HID * 32;
#pragma unroll
    for (int nt = 0; nt < 8; ++nt) {
        af[nt] = *(const short8*)(wp + (nt * 16 + lr) * 32 + lg * 8);
        cv[nt] = *(const f32x4*)(cc + l * HID + nt * 16 + lg * 4);
    }
    for (int it = 0; it < 4; ++it) {
        int e0 = ce0 + blockIdx.x * 256 + wv * 64 + it * 16;
        int e = e0 + lr;
        short8 b = {0, 0, 0, 0, 0, 0, 0, 0};
        if (e < ce1 && lg < 2) b = *(const short8*)(ea_sb + (long)e * EDGE_DIM + lg * 8);
        f32x4 acc[8];
#pragma unroll
        for (int nt = 0; nt < 8; ++nt) acc[nt] = (f32x4){0.f, 0.f, 0.f, 0.f};
#pragma unroll
        for (int nt = 0; nt < 8; ++nt)
            acc[nt] = __builtin_amdgcn_mfma_f32_16x16x32_bf16(af[nt], b, acc[nt], 0, 0, 0);
        if (e < ce1) {
            ushort_t* gp = g + (long)(e - ce0) * HID + lg * 4;
#pragma unroll
            for (int nt = 0; nt < 8; ++nt) {
                s16x4 o;
#pragma unroll
                for (int r = 0; r < 4; ++r) o[r] = (short)f2b(acc[nt][r] + cv[nt][r]);
                *(s16x4*)(gp + nt * 16) = o;
            }
        }
    }
}

// ---------------- per-layer aggregation over chunk [ce0,ce1), 8 nodes/block --------
__global__ __launch_bounds__(512) void k_edge2(const ushort_t* __restrict__ g,
                                               const int* __restrict__ src_s,
                                               const int* __restrict__ offs,
                                               const int* __restrict__ deg,
                                               const float* __restrict__ h,
                                               const ushort_t* __restrict__ hb,
                                               const float* __restrict__ epsv,
                                               float* __restrict__ zacc,
                                               ushort_t* __restrict__ z,
                                               int l, int ce0, int ce1, int mode) {
    int lane = threadIdx.x & 63;
    int node = blockIdx.x * 8 + (threadIdx.x >> 6);
    if (node >= N_NODES) return;
    bool first = mode & 1, last = (mode & 2) != 0;
    int ch0 = lane * 2;
    int s0 = offs[node];
    int dg = deg[node];
    int e_lo = max(s0, ce0);
    int e_hi = min(s0 + dg, ce1);
    if (e_lo >= e_hi && !first && !last) return;
    float a0 = 0.f, a1 = 0.f;
    int i = e_lo;
    for (; i + 4 <= e_hi; i += 4) {
        long eg = (long)(i - ce0);
        int sa = src_s[i], sb_ = src_s[i + 1], sc_ = src_s[i + 2], sd_ = src_s[i + 3];
        unsigned ga = *(const unsigned*)(g + eg * HID + ch0);
        unsigned gb = *(const unsigned*)(g + (eg + 1) * HID + ch0);
        unsigned gc = *(const unsigned*)(g + (eg + 2) * HID + ch0);
        unsigned gd = *(const unsigned*)(g + (eg + 3) * HID + ch0);
        unsigned ha = *(const unsigned*)(hb + (long)sa * HID + ch0);
        unsigned hbv = *(const unsigned*)(hb + (long)sb_ * HID + ch0);
        unsigned hc = *(const unsigned*)(hb + (long)sc_ * HID + ch0);
        unsigned hd = *(const unsigned*)(hb + (long)sd_ * HID + ch0);
        a0 += fmaxf(b2f((ushort_t)(ha & 0xffff)) + b2f((ushort_t)(ga & 0xffff)), 0.f);
        a1 += fmaxf(b2f((ushort_t)(ha >> 16)) + b2f((ushort_t)(ga >> 16)), 0.f);
        a0 += fmaxf(b2f((ushort_t)(hbv & 0xffff)) + b2f((ushort_t)(gb & 0xffff)), 0.f);
        a1 += fmaxf(b2f((ushort_t)(hbv >> 16)) + b2f((ushort_t)(gb >> 16)), 0.f);
        a0 += fmaxf(b2f((ushort_t)(hc & 0xffff)) + b2f((ushort_t)(gc & 0xffff)), 0.f);
        a1 += fmaxf(b2f((ushort_t)(hc >> 16)) + b2f((ushort_t)(gc >> 16)), 0.f);
        a0 += fmaxf(b2f((ushort_t)(hd & 0xffff)) + b2f((ushort_t)(gd & 0xffff)), 0.f);
        a1 += fmaxf(b2f((ushort_t)(hd >> 16)) + b2f((ushort_t)(gd >> 16)), 0.f);
    }
    for (; i < e_hi; ++i) {
        long eg = (long)(i - ce0);
        int s = src_s[i];
        unsigned gv = *(const unsigned*)(g + eg * HID + ch0);
        unsigned hv = *(const unsigned*)(hb + (long)s * HID + ch0);
        a0 += fmaxf(b2f((ushort_t)(hv & 0xffff)) + b2f((ushort_t)(gv & 0xffff)), 0.f);
        a1 += fmaxf(b2f((ushort_t)(hv >> 16)) + b2f((ushort_t)(gv >> 16)), 0.f);
    }
    if (!first) {
        f32x2 p = *(const f32x2*)(zacc + (long)node * HID + ch0);
        a0 += p[0]; a1 += p[1];
    }
    if (last) {
        float ep1 = 1.f + epsv[l];
        f32x2 hn = *(const f32x2*)(h + (long)node * HID + ch0);
        unsigned zz = (unsigned)f2b(fmaf(ep1, hn[0], a0)) |
                      ((unsigned)f2b(fmaf(ep1, hn[1], a1)) << 16);
        *(unsigned*)(z + (long)node * HID + ch0) = zz;
    } else {
        *(f32x2*)(zacc + (long)node * HID + ch0) = (f32x2){a0, a1};
    }
}

// ---------------- mlp1: one 64-node tile/block, LDS weight half (A), packed stores ----
__global__ __launch_bounds__(256) void k_mlp1(const ushort_t* __restrict__ z,
                                              const ushort_t* __restrict__ w1T,
                                              const float* __restrict__ b1,
                                              ushort_t* __restrict__ ibuf, int l) {
    __shared__ __align__(16) short lBw[128 * HID];  // 32 KB: 128 feats x K=128
    int half = blockIdx.x & 1;
    int tile = blockIdx.x >> 1;  // [0, MT64)
    const ushort_t* wl = w1T + (long)l * HID2 * HID + (long)half * 128 * HID;
    for (int c = threadIdx.x; c < 128 * HID / 8; c += 256) {
        int row = c >> 4, k0 = (c & 15) * 8;
        short8 v = *(const short8*)(wl + row * HID + k0);
        int gsw = (k0 >> 3) ^ (row & 7);
        *(short8*)&lBw[row * HID + gsw * 8] = v;
    }
    int wv = threadIdx.x >> 6, l6 = threadIdx.x & 63;
    int lr = l6 & 15, lg = l6 >> 4;
    int node = tile * 64 + wv * 16 + lr;
    short8 b[4];
    const ushort_t* zr = z + (long)node * HID;
#pragma unroll
    for (int kt = 0; kt < 4; ++kt) b[kt] = *(const short8*)(zr + kt * 32 + lg * 8);
    __syncthreads();
#pragma unroll
    for (int nt = 0; nt < 8; ++nt) {
        f32x4 acc = (f32x4){0.f, 0.f, 0.f, 0.f};
        int brow = nt * 16 + lr;
#pragma unroll
        for (int kt = 0; kt < 4; ++kt) {
            short8 af = *(const short8*)&lBw[brow * HID + (((kt * 4 + lg) ^ (brow & 7)) << 3)];
            acc = __builtin_amdgcn_mfma_f32_16x16x32_bf16(af, b[kt], acc, 0, 0, 0);
        }
        f32x4 bv = *(const f32x4*)(b1 + l * HID2 + half * 128 + nt * 16 + lg * 4);
        s16x4 o;
#pragma unroll
        for (int r = 0; r < 4; ++r) o[r] = (short)f2b(fmaxf(acc[r] + bv[r], 0.f));
        *(s16x4*)(ibuf + (long)node * HID2 + half * 128 + nt * 16 + lg * 4) = o;
    }
}

// ---------------- mlp2: one 64-node tile/block, LDS weight half (A), BN stats via LDS ----
__global__ __launch_bounds__(256) void k_mlp2(const ushort_t* __restrict__ ibuf,
                                              const ushort_t* __restrict__ w2T,
                                              const float* __restrict__ b2,
                                              ushort_t* __restrict__ z2,
                                              float* __restrict__ bnstats, int l) {
    __shared__ __align__(16) short lBw[64 * HID2];  // 32 KB: 64 feats x K=256
    __shared__ float lStat[2][64];
    int half = blockIdx.x & 1;
    int tile = blockIdx.x >> 1;
    const ushort_t* wl = w2T + (long)l * HID * HID2 + (long)half * 64 * HID2;
    for (int c = threadIdx.x; c < 64 * HID2 / 8; c += 256) {
        int row = c >> 5, k0 = (c & 31) * 8;
        short8 v = *(const short8*)(wl + row * HID2 + k0);
        int gsw = (k0 >> 3) ^ (row & 7);
        *(short8*)&lBw[row * HID2 + gsw * 8] = v;
    }
    if (threadIdx.x < 128) lStat[threadIdx.x >> 6][threadIdx.x & 63] = 0.f;
    int wv = threadIdx.x >> 6, l6 = threadIdx.x & 63;
    int lr = l6 & 15, lg = l6 >> 4;
    int node = tile * 64 + wv * 16 + lr;
    bool valid = node < N_NODES;
    short8 b[8];
    const ushort_t* ir = ibuf + (long)node * HID2;
#pragma unroll
    for (int kt = 0; kt < 8; ++kt) b[kt] = *(const short8*)(ir + kt * 32 + lg * 8);
    __syncthreads();
#pragma unroll
    for (int nt = 0; nt < 4; ++nt) {
        f32x4 acc = (f32x4){0.f, 0.f, 0.f, 0.f};
        int brow = nt * 16 + lr;
#pragma unroll
        for (int kt = 0; kt < 8; ++kt) {
            short8 af = *(const short8*)&lBw[brow * HID2 + (((kt * 4 + lg) ^ (brow & 7)) << 3)];
            acc = __builtin_amdgcn_mfma_f32_16x16x32_bf16(af, b[kt], acc, 0, 0, 0);
        }
        f32x4 bv = *(const f32x4*)(b2 + l * HID + half * 64 + nt * 16 + lg * 4);
        s16x4 o;
#pragma unroll
        for (int r = 0; r < 4; ++r) {
            float v = acc[r] + bv[r];
            o[r] = (short)f2b(v);
            float s = valid ? v : 0.f, q = valid ? v * v : 0.f;
            s += __shfl_xor(s, 1); s += __shfl_xor(s, 2);
            s += __shfl_xor(s, 4); s += __shfl_xor(s, 8);
            q += __shfl_xor(q, 1); q += __shfl_xor(q, 2);
            q += __shfl_xor(q, 4); q += __shfl_xor(q, 8);
            if (lr == 0) {
                int f = nt * 16 + lg * 4 + r;  // feat within half [0,64)
                atomicAdd(&lStat[0][f], s);
                atomicAdd(&lStat[1][f], q);
            }
        }
        *(s16x4*)(z2 + (long)node * HID + half * 64 + nt * 16 + lg * 4) = o;
    }
    __syncthreads();
    if (threadIdx.x < 128) {
        int which = threadIdx.x >> 6, f = threadIdx.x & 63;
        atomicAdd(&bnstats[(which * NLAYER + l) * HID + half * 64 + f], lStat[which][f]);
    }
}

// ---------------- BN apply + residual + relu ----------------
__global__ __launch_bounds__(1024) void k_resid(const ushort_t* __restrict__ z2,
                                                const float* __restrict__ bnstats,
                                                const float* __restrict__ bng,
                                                const float* __restrict__ bnb,
                                                float* __restrict__ h,
                                                ushort_t* __restrict__ hb, int l) {
    long i = (long)blockIdx.x * 1024 + threadIdx.x;
    int c = (int)(i & (HID - 1));
    float inv = 1.f / (float)N_NODES;
    float mu = bnstats[l * HID + c] * inv;
    float var = bnstats[(NLAYER + l) * HID + c] * inv - mu * mu;
    float A = rsqrtf(var + 1e-5f) * bng[l * HID + c];
    float B = bnb[l * HID + c] - mu * A;
    float v = fmaf(b2f(z2[i]), A, B) + h[i];
    v = fmaxf(v, 0.f);
    h[i] = v;
    hb[i] = f2b(v);
}

// ---------------- pooling (per-block binary search for segment bounds) --------------
__global__ __launch_bounds__(512) void k_pool(const float* __restrict__ h,
                                              const int* __restrict__ batch,
                                              float* __restrict__ pooled,
                                              float* __restrict__ outp) {
    __shared__ float red[4][HID];
    __shared__ int sb[2];
    int g = blockIdx.x;
    if (threadIdx.x < 2) {
        int target = g + threadIdx.x;
        int lo = 0, hi = N_NODES;
        while (lo < hi) { int mid = (lo + hi) >> 1; if (batch[mid] < target) lo = mid + 1; else hi = mid; }
        sb[threadIdx.x] = lo;
    }
    __syncthreads();
    int st = sb[0], en = sb[1];
    int ch = threadIdx.x & 127, seg = threadIdx.x >> 7;
    float s = 0.f;
    for (int i = st + seg; i < en; i += 4) s += h[(long)i * HID + ch];
    red[seg][ch] = s;
    __syncthreads();
    if (seg == 0) {
        float p = (red[0][ch] + red[1][ch] + red[2][ch] + red[3][ch]) /
                  fmaxf((float)(en - st), 1.f);
        pooled[g * HID + ch] = p;
        outp[g * HID + ch] = p;
    }
}

// ---------------- output MLP ----------------
__global__ __launch_bounds__(128) void k_outmlp(const float* __restrict__ pooled,
                                                const float* __restrict__ w1,
                                                const float* __restrict__ b1,
                                                const float* __restrict__ w2,
                                                const float* __restrict__ b2,
                                                float* __restrict__ outl) {
    __shared__ float pr[HID];
    __shared__ float hid[64];
    int g = blockIdx.x, t = threadIdx.x;
    pr[t] = pooled[g * HID + t];
    __syncthreads();
    if (t < 64) {
        float a = b1[t];
        for (int k = 0; k < HID; ++k) a = fmaf(pr[k], w1[k * 64 + t], a);
        hid[t] = fmaxf(a, 0.f);
    }
    __syncthreads();
    float a = b2[t];
#pragma unroll
    for (int j = 0; j < 64; ++j) a = fmaf(hid[j], w2[j * HID + t], a);
    outl[g * HID + t] = a;
}

// =====================================================================================
extern "C" void kernel_launch(void* const* d_in, const int* in_sizes, int n_in,
                              void* d_out, int out_size, void* d_ws, size_t ws_size,
                              hipStream_t stream) {
    (void)in_sizes; (void)n_in; (void)out_size;
    const float* x      = (const float*)d_in[0];
    const int*   ei     = (const int*)d_in[1];
    const float* ea     = (const float*)d_in[2];
    const int*   batch  = (const int*)d_in[3];
    const float* node_w = (const float*)d_in[4];
    const float* node_b = (const float*)d_in[5];
    const float* edge_w = (const float*)d_in[6];
    const float* edge_b = (const float*)d_in[7];
    const float* epsv   = (const float*)d_in[8];
    const float* lin_w  = (const float*)d_in[9];
    const float* lin_b  = (const float*)d_in[10];
    const float* m1w    = (const float*)d_in[11];
    const float* m1b    = (const float*)d_in[12];
    const float* m2w    = (const float*)d_in[13];
    const float* m2b    = (const float*)d_in[14];
    const float* bng    = (const float*)d_in[15];
    const float* bnb    = (const float*)d_in[16];
    const float* ow1    = (const float*)d_in[17];
    const float* ob1    = (const float*)d_in[18];
    const float* ow2    = (const float*)d_in[19];
    const float* ob2    = (const float*)d_in[20];

    const size_t MiB = 1024ull * 1024ull;
    int NC;
    if      (ws_size >= 275 * MiB) NC = 1;
    else if (ws_size >= 193 * MiB) NC = 2;
    else if (ws_size >= 152 * MiB) NC = 4;
    else                           NC = 8;
    int EC = (N_EDGES + NC - 1) / NC;

    char* ws = (char*)d_ws;
    size_t off = 0;
    auto alloc = [&](size_t bytes) -> char* {
        char* p = ws + off;
        off = (off + bytes + 255) & ~(size_t)255;
        return p;
    };
    float*    h       = (float*)alloc((size_t)NPAD * HID * 4);
    ushort_t* hb      = (ushort_t*)alloc((size_t)NPAD * HID * 2);
    ushort_t* z       = (ushort_t*)alloc((size_t)NPAD * HID * 2);   // reused as z2
    ushort_t* ibuf    = (ushort_t*)alloc((size_t)NPAD * HID2 * 2);  // aliased: zacc, perm
    ushort_t* ea_sb   = (ushort_t*)alloc((size_t)N_EDGES * EDGE_DIM * 2 + 64);
    ushort_t* g       = (ushort_t*)alloc((size_t)EC * HID * 2);
    int*      src_s   = (int*)alloc((size_t)N_EDGES * 4);
    int*      deg     = (int*)alloc((size_t)N_NODES * 4);
    int*      offs    = (int*)alloc((size_t)N_NODES * 4);
    int*      cursor  = (int*)alloc((size_t)N_NODES * 4);
    int*      bsum    = (int*)alloc(64 * 4);
    ushort_t* WcbT    = (ushort_t*)alloc((size_t)NLAYER * HID * 32 * 2);
    float*    cc      = (float*)alloc((size_t)NLAYER * HID * 4);
    ushort_t* w0T     = (ushort_t*)alloc((size_t)HID * IN_CH * 2);
    ushort_t* w1T     = (ushort_t*)alloc((size_t)NLAYER * HID2 * HID * 2);
    ushort_t* w2T     = (ushort_t*)alloc((size_t)NLAYER * HID * HID2 * 2);
    float*    bnstats = (float*)alloc((size_t)2 * NLAYER * HID * 4);
    float*    pooled  = (float*)alloc((size_t)NGRAPH * HID * 4);
    float*    zacc    = (float*)ibuf;  // alias: chunked-edge accumulator
    int*      perm    = (int*)ibuf;    // alias: CSR build only
    ushort_t* z2      = z;

    (void)hipMemsetAsync(deg, 0, (size_t)N_NODES * 4, stream);
    (void)hipMemsetAsync(cursor, 0, (size_t)N_NODES * 4, stream);
    (void)hipMemsetAsync(bnstats, 0, (size_t)2 * NLAYER * HID * 4, stream);

    k_transpose_all<<<1280, 256, 0, stream>>>(node_w, m1w, m2w, w0T, w1T, w2T);
    k_combine<<<NLAYER, HID, 0, stream>>>(edge_w, edge_b, lin_w, lin_b, WcbT, cc);

    k_hist<<<N_EDGES / 1024, 256, 0, stream>>>(ei, deg);
    k_scan1<<<49, 1024, 0, stream>>>(deg, offs, bsum);
    k_scan2<<<1, 64, 0, stream>>>(bsum, 49);
    k_scan3<<<49, 1024, 0, stream>>>(offs, bsum);
    k_scatter1<<<N_EDGES / 1024, 256, 0, stream>>>(ei, offs, cursor, perm);
    k_gather<<<N_EDGES / 256, 256, 0, stream>>>(perm, ei, ea, src_s, ea_sb);

    k_node_enc<<<NPAD / 64, 256, 0, stream>>>(x, w0T, node_b, h, hb);

    for (int l = 0; l < NLAYER; ++l) {
        for (int c = 0; c < NC; ++c) {
            int ce0 = c * EC;
            int ce1 = (ce0 + EC < N_EDGES) ? (ce0 + EC) : N_EDGES;
            int nblk = (ce1 - ce0 + 255) / 256;
            int mode = (c == 0 ? 1 : 0) | (c == NC - 1 ? 2 : 0);
            k_edgegemm<<<nblk, 256, 0, stream>>>(ea_sb, WcbT, cc, g, l, ce0, ce1);
            k_edge2<<<(N_NODES + 7) / 8, 512, 0, stream>>>(g, src_s, offs, deg, h, hb,
                                                           epsv, zacc, z, l, ce0, ce1, mode);
        }
        k_mlp1<<<MT64 * 2, 256, 0, stream>>>(z, w1T, m1b, ibuf, l);
        k_mlp2<<<MT64 * 2, 256, 0, stream>>>(ibuf, w2T, m2b, z2, bnstats, l);
        k_resid<<<(N_NODES * HID) / 1024, 1024, 0, stream>>>(z2, bnstats, bng, bnb, h, hb, l);
    }

    k_pool<<<NGRAPH, 512, 0, stream>>>(h, batch, pooled, (float*)d_out + NGRAPH * HID);
    k_outmlp<<<NGRAPH, HID, 0, stream>>>(pooled, ow1, ob1, ow2, ob2, (float*)d_out);
}

// Round 18
// 1003.573 us; speedup vs baseline: 1.1923x; 1.0727x over previous
//
#include <hip/hip_runtime.h>

#define N_NODES  50000
#define NPAD     50048
#define N_EDGES  640000
#define IN_CH    64
#define EDGE_DIM 16
#define HID      128
#define HID2     256
#define NLAYER   5
#define NGRAPH   128
#define MT64     (NPAD / 64)

typedef unsigned short ushort_t;
typedef __attribute__((ext_vector_type(8))) short short8;
typedef __attribute__((ext_vector_type(4))) short s16x4;
typedef __attribute__((ext_vector_type(4))) float f32x4;
typedef __attribute__((ext_vector_type(2))) float f32x2;
typedef __attribute__((ext_vector_type(4))) int i32x4;

__device__ __forceinline__ float b2f(ushort_t u) {
    union { unsigned v; float f; } x; x.v = ((unsigned)u) << 16; return x.f;
}
__device__ __forceinline__ ushort_t f2b(float f) {
    union { float f; unsigned u; } x; x.f = f;
    unsigned u = x.u;
    unsigned r = (u + 0x7FFFu + ((u >> 16) & 1u)) >> 16;
    return (ushort_t)r;
}

// ---------------- prep: all three weight transposes in one launch ----------------
__global__ void k_transpose_all(const float* __restrict__ w0,   // [IN_CH][HID]
                                const float* __restrict__ w1,   // [L][HID][HID2]
                                const float* __restrict__ w2,   // [L][HID2][HID]
                                ushort_t* __restrict__ w0T,
                                ushort_t* __restrict__ w1T,
                                ushort_t* __restrict__ w2T) {
    const long n0 = (long)IN_CH * HID;
    const long n1 = (long)NLAYER * HID * HID2;
    const long n2 = (long)NLAYER * HID2 * HID;
    long total = n0 + n1 + n2;
    for (long i = (long)blockIdx.x * blockDim.x + threadIdx.x; i < total;
         i += (long)gridDim.x * blockDim.x) {
        if (i < n0) {
            int k = (int)(i / HID), n = (int)(i - (long)k * HID);
            w0T[(long)n * IN_CH + k] = f2b(w0[i]);
        } else if (i < n0 + n1) {
            long j = i - n0;
            int b = (int)(j / ((long)HID * HID2));
            int rem = (int)(j - (long)b * HID * HID2);
            int k = rem / HID2, n = rem - k * HID2;
            w1T[(long)b * HID * HID2 + (long)n * HID + k] = f2b(w1[j]);
        } else {
            long j = i - n0 - n1;
            int b = (int)(j / ((long)HID2 * HID));
            int rem = (int)(j - (long)b * HID2 * HID);
            int k = rem / HID, n = rem - k * HID;
            w2T[(long)b * HID2 * HID + (long)n * HID2 + k] = f2b(w2[j]);
        }
    }
}

// WcbT bf16 [l][col=128][k=32 zero-padded] + cc f32
__global__ __launch_bounds__(128) void k_combine(const float* __restrict__ ew,
                                                 const float* __restrict__ eb,
                                                 const float* __restrict__ lw,
                                                 const float* __restrict__ lb,
                                                 ushort_t* __restrict__ WcbT,
                                                 float* __restrict__ cc) {
    int l = blockIdx.x, j = threadIdx.x;
    float accW[EDGE_DIM];
#pragma unroll
    for (int k = 0; k < EDGE_DIM; ++k) accW[k] = 0.f;
    float accc = 0.f;
    for (int i = 0; i < HID; ++i) {
        float lwv = lw[((long)l * HID + i) * HID + j];
        accc = fmaf(eb[i], lwv, accc);
#pragma unroll
        for (int k = 0; k < EDGE_DIM; ++k)
            accW[k] = fmaf(ew[k * HID + i], lwv, accW[k]);
    }
    ushort_t* wp = WcbT + ((long)l * HID + j) * 32;
#pragma unroll
    for (int k = 0; k < EDGE_DIM; ++k) wp[k] = f2b(accW[k]);
#pragma unroll
    for (int k = EDGE_DIM; k < 32; ++k) wp[k] = 0;
    cc[l * HID + j] = accc + lb[l * HID + j];
}

// ---------------- CSR build (4 edges/thread: 4 atomics in flight) ----------------
__global__ __launch_bounds__(256) void k_hist(const int* __restrict__ ei, int* __restrict__ deg) {
    int e0 = (blockIdx.x * 256 + threadIdx.x) * 4;
    if (e0 >= N_EDGES) return;
    i32x4 d = *(const i32x4*)(ei + N_EDGES + e0);
    atomicAdd(&deg[d.x], 1);
    atomicAdd(&deg[d.y], 1);
    atomicAdd(&deg[d.z], 1);
    atomicAdd(&deg[d.w], 1);
}

__global__ __launch_bounds__(1024) void k_scan1(const int* __restrict__ deg,
                                                int* __restrict__ offs, int* __restrict__ bsum) {
    __shared__ int s[1024];
    int i = blockIdx.x * 1024 + threadIdx.x;
    int v = (i < N_NODES) ? deg[i] : 0;
    s[threadIdx.x] = v;
    __syncthreads();
    for (int off = 1; off < 1024; off <<= 1) {
        int t = (threadIdx.x >= off) ? s[threadIdx.x - off] : 0;
        __syncthreads();
        s[threadIdx.x] += t;
        __syncthreads();
    }
    if (i < N_NODES) offs[i] = s[threadIdx.x] - v;  // exclusive
    if (threadIdx.x == 1023) bsum[blockIdx.x] = s[1023];
}

// 64-thread wave inclusive-scan over nb<=64 entries -> exclusive in place
__global__ void k_scan2(int* __restrict__ bsum, int nb) {
    int t = threadIdx.x;
    int v = (t < nb) ? bsum[t] : 0;
    int x = v;
#pragma unroll
    for (int off = 1; off < 64; off <<= 1) {
        int y = __shfl_up(x, off);
        if ((t & 63) >= off) x += y;
    }
    if (t < nb) bsum[t] = x - v;  // exclusive
}

__global__ __launch_bounds__(1024) void k_scan3(int* __restrict__ offs, const int* __restrict__ bsum) {
    int i = blockIdx.x * 1024 + threadIdx.x;
    if (i < N_NODES) offs[i] += bsum[blockIdx.x];
}

// pos computation + 4B perm scatter, 4 edges/thread (4 atomics+stores in flight)
__global__ __launch_bounds__(256) void k_scatter1(const int* __restrict__ ei,
                                                  const int* __restrict__ offs,
                                                  int* __restrict__ cursor,
                                                  int* __restrict__ perm) {
    int e0 = (blockIdx.x * 256 + threadIdx.x) * 4;
    if (e0 >= N_EDGES) return;
    i32x4 d = *(const i32x4*)(ei + N_EDGES + e0);
    int p0 = offs[d.x] + atomicAdd(&cursor[d.x], 1);
    int p1 = offs[d.y] + atomicAdd(&cursor[d.y], 1);
    int p2 = offs[d.z] + atomicAdd(&cursor[d.z], 1);
    int p3 = offs[d.w] + atomicAdd(&cursor[d.w], 1);
    perm[p0] = e0;
    perm[p1] = e0 + 1;
    perm[p2] = e0 + 2;
    perm[p3] = e0 + 3;
}

// gather reads, coalesced writes
__global__ __launch_bounds__(256) void k_gather(const int* __restrict__ perm,
                                                const int* __restrict__ ei,
                                                const float* __restrict__ ea,
                                                int* __restrict__ src_s,
                                                ushort_t* __restrict__ ea_sb) {
    int p = blockIdx.x * 256 + threadIdx.x;
    if (p >= N_EDGES) return;
    int e = perm[p];
    src_s[p] = ei[e];
    const f32x4* srcp = (const f32x4*)(ea + (long)e * EDGE_DIM);
    f32x4 v0 = srcp[0], v1 = srcp[1], v2 = srcp[2], v3 = srcp[3];
    short8 o0, o1;
#pragma unroll
    for (int j = 0; j < 4; ++j) {
        o0[j] = (short)f2b(v0[j]); o0[4 + j] = (short)f2b(v1[j]);
        o1[j] = (short)f2b(v2[j]); o1[4 + j] = (short)f2b(v3[j]);
    }
    short8* dst = (short8*)(ea_sb + (long)p * EDGE_DIM);
    dst[0] = o0;
    dst[1] = o1;
}

// ---------------- node encoder: h = relu(x @ node_w + node_b), f32 + bf16 out --------
__global__ __launch_bounds__(256) void k_node_enc(const float* __restrict__ x,
                                                  const ushort_t* __restrict__ w0T,
                                                  const float* __restrict__ nb,
                                                  float* __restrict__ h,
                                                  ushort_t* __restrict__ hb) {
    __shared__ __align__(16) short lB[HID * IN_CH];
    for (int c = threadIdx.x; c < HID * IN_CH / 8; c += 256) {
        int row = c >> 3, k0 = (c & 7) * 8;
        short8 v = *(const short8*)(w0T + row * IN_CH + k0);
        int g = (k0 >> 3) ^ (row & 7);
        *(short8*)&lB[row * IN_CH + g * 8] = v;
    }
    __syncthreads();
    int wv = threadIdx.x >> 6, l6 = threadIdx.x & 63;
    int lr = l6 & 15, lg = l6 >> 4;
    int grow = blockIdx.x * 64 + wv * 16 + lr;
    f32x4 acc[8];
#pragma unroll
    for (int nt = 0; nt < 8; ++nt) acc[nt] = (f32x4){0.f, 0.f, 0.f, 0.f};
#pragma unroll
    for (int kt = 0; kt < 2; ++kt) {
        int kk = kt * 32 + lg * 8;
        short8 a = {0, 0, 0, 0, 0, 0, 0, 0};
        if (grow < N_NODES) {
            const float* xr = x + (long)grow * IN_CH + kk;
            f32x4 v0 = *(const f32x4*)xr;
            f32x4 v1 = *(const f32x4*)(xr + 4);
#pragma unroll
            for (int j = 0; j < 4; ++j) { a[j] = (short)f2b(v0[j]); a[4 + j] = (short)f2b(v1[j]); }
        }
#pragma unroll
        for (int nt = 0; nt < 8; ++nt) {
            int brow = nt * 16 + lr;
            short8 b = *(const short8*)&lB[brow * IN_CH + (((kk >> 3) ^ (brow & 7)) << 3)];
            acc[nt] = __builtin_amdgcn_mfma_f32_16x16x32_bf16(a, b, acc[nt], 0, 0, 0);
        }
    }
    int orow0 = blockIdx.x * 64 + wv * 16 + lg * 4;
#pragma unroll
    for (int nt = 0; nt < 8; ++nt) {
        int col = nt * 16 + lr;
        float bias = nb[col];
#pragma unroll
        for (int r = 0; r < 4; ++r) {
            int row = orow0 + r;
            if (row < N_NODES) {
                float v = fmaxf(acc[nt][r] + bias, 0.f);
                h[(long)row * HID + col] = v;
                hb[(long)row * HID + col] = f2b(v);
            }
        }
    }
}

// ---------------- per-layer edge GEMM (chunk [ce0,ce1)) ----------------
__global__ __launch_bounds__(256) void k_edgegemm(const ushort_t* __restrict__ ea_sb,
                                                  const ushort_t* __restrict__ WcbT,
                                                  const float* __restrict__ cc,
                                                  ushort_t* __restrict__ g, int l,
                                                  int ce0, int ce1) {
    int wv = threadIdx.x >> 6, l6 = threadIdx.x & 63;
    int lr = l6 & 15, lg = l6 >> 4;
    short8 af[8];
    f32x4 cv[8];
    const ushort_t* wp = WcbT + (long)l * HID * 32;
#pragma unroll
    for (int nt = 0; nt < 8; ++nt) {
        af[nt] = *(const short8*)(wp + (nt * 16 + lr) * 32 + lg * 8);
        cv[nt] = *(const f32x4*)(cc + l * HID + nt * 16 + lg * 4);
    }
    for (int it = 0; it < 4; ++it) {
        int e0 = ce0 + blockIdx.x * 256 + wv * 64 + it * 16;
        int e = e0 + lr;
        short8 b = {0, 0, 0, 0, 0, 0, 0, 0};
        if (e < ce1 && lg < 2) b = *(const short8*)(ea_sb + (long)e * EDGE_DIM + lg * 8);
        f32x4 acc[8];
#pragma unroll
        for (int nt = 0; nt < 8; ++nt) acc[nt] = (f32x4){0.f, 0.f, 0.f, 0.f};
#pragma unroll
        for (int nt = 0; nt < 8; ++nt)
            acc[nt] = __builtin_amdgcn_mfma_f32_16x16x32_bf16(af[nt], b, acc[nt], 0, 0, 0);
        if (e < ce1) {
            ushort_t* gp = g + (long)(e - ce0) * HID + lg * 4;
#pragma unroll
            for (int nt = 0; nt < 8; ++nt) {
                s16x4 o;
#pragma unroll
                for (int r = 0; r < 4; ++r) o[r] = (short)f2b(acc[nt][r] + cv[nt][r]);
                *(s16x4*)(gp + nt * 16) = o;
            }
        }
    }
}

// ---------------- per-layer aggregation over chunk [ce0,ce1), 8 nodes/block --------
__global__ __launch_bounds__(512) void k_edge2(const ushort_t* __restrict__ g,
                                               const int* __restrict__ src_s,
                                               const int* __restrict__ offs,
                                               const int* __restrict__ deg,
                                               const float* __restrict__ h,
                                               const ushort_t* __restrict__ hb,
                                               const float* __restrict__ epsv,
                                               float* __restrict__ zacc,
                                               ushort_t* __restrict__ z,
                                               int l, int ce0, int ce1, int mode) {
    int lane = threadIdx.x & 63;
    int node = blockIdx.x * 8 + (threadIdx.x >> 6);
    if (node >= N_NODES) return;
    bool first = mode & 1, last = (mode & 2) != 0;
    int ch0 = lane * 2;
    int s0 = offs[node];
    int dg = deg[node];
    int e_lo = max(s0, ce0);
    int e_hi = min(s0 + dg, ce1);
    if (e_lo >= e_hi && !first && !last) return;
    float a0 = 0.f, a1 = 0.f;
    int i = e_lo;
    for (; i + 4 <= e_hi; i += 4) {
        long eg = (long)(i - ce0);
        int sa = src_s[i], sb_ = src_s[i + 1], sc_ = src_s[i + 2], sd_ = src_s[i + 3];
        unsigned ga = *(const unsigned*)(g + eg * HID + ch0);
        unsigned gb = *(const unsigned*)(g + (eg + 1) * HID + ch0);
        unsigned gc = *(const unsigned*)(g + (eg + 2) * HID + ch0);
        unsigned gd = *(const unsigned*)(g + (eg + 3) * HID + ch0);
        unsigned ha = *(const unsigned*)(hb + (long)sa * HID + ch0);
        unsigned hbv = *(const unsigned*)(hb + (long)sb_ * HID + ch0);
        unsigned hc = *(const unsigned*)(hb + (long)sc_ * HID + ch0);
        unsigned hd = *(const unsigned*)(hb + (long)sd_ * HID + ch0);
        a0 += fmaxf(b2f((ushort_t)(ha & 0xffff)) + b2f((ushort_t)(ga & 0xffff)), 0.f);
        a1 += fmaxf(b2f((ushort_t)(ha >> 16)) + b2f((ushort_t)(ga >> 16)), 0.f);
        a0 += fmaxf(b2f((ushort_t)(hbv & 0xffff)) + b2f((ushort_t)(gb & 0xffff)), 0.f);
        a1 += fmaxf(b2f((ushort_t)(hbv >> 16)) + b2f((ushort_t)(gb >> 16)), 0.f);
        a0 += fmaxf(b2f((ushort_t)(hc & 0xffff)) + b2f((ushort_t)(gc & 0xffff)), 0.f);
        a1 += fmaxf(b2f((ushort_t)(hc >> 16)) + b2f((ushort_t)(gc >> 16)), 0.f);
        a0 += fmaxf(b2f((ushort_t)(hd & 0xffff)) + b2f((ushort_t)(gd & 0xffff)), 0.f);
        a1 += fmaxf(b2f((ushort_t)(hd >> 16)) + b2f((ushort_t)(gd >> 16)), 0.f);
    }
    for (; i < e_hi; ++i) {
        long eg = (long)(i - ce0);
        int s = src_s[i];
        unsigned gv = *(const unsigned*)(g + eg * HID + ch0);
        unsigned hv = *(const unsigned*)(hb + (long)s * HID + ch0);
        a0 += fmaxf(b2f((ushort_t)(hv & 0xffff)) + b2f((ushort_t)(gv & 0xffff)), 0.f);
        a1 += fmaxf(b2f((ushort_t)(hv >> 16)) + b2f((ushort_t)(gv >> 16)), 0.f);
    }
    if (!first) {
        f32x2 p = *(const f32x2*)(zacc + (long)node * HID + ch0);
        a0 += p[0]; a1 += p[1];
    }
    if (last) {
        float ep1 = 1.f + epsv[l];
        f32x2 hn = *(const f32x2*)(h + (long)node * HID + ch0);
        unsigned zz = (unsigned)f2b(fmaf(ep1, hn[0], a0)) |
                      ((unsigned)f2b(fmaf(ep1, hn[1], a1)) << 16);
        *(unsigned*)(z + (long)node * HID + ch0) = zz;
    } else {
        *(f32x2*)(zacc + (long)node * HID + ch0) = (f32x2){a0, a1};
    }
}

// ---------------- mlp1: one 64-node tile/block, LDS weight half (A), packed stores ----
__global__ __launch_bounds__(256) void k_mlp1(const ushort_t* __restrict__ z,
                                              const ushort_t* __restrict__ w1T,
                                              const float* __restrict__ b1,
                                              ushort_t* __restrict__ ibuf, int l) {
    __shared__ __align__(16) short lBw[128 * HID];  // 32 KB: 128 feats x K=128
    int half = blockIdx.x & 1;
    int tile = blockIdx.x >> 1;  // [0, MT64)
    const ushort_t* wl = w1T + (long)l * HID2 * HID + (long)half * 128 * HID;
    for (int c = threadIdx.x; c < 128 * HID / 8; c += 256) {
        int row = c >> 4, k0 = (c & 15) * 8;
        short8 v = *(const short8*)(wl + row * HID + k0);
        int gsw = (k0 >> 3) ^ (row & 7);
        *(short8*)&lBw[row * HID + gsw * 8] = v;
    }
    int wv = threadIdx.x >> 6, l6 = threadIdx.x & 63;
    int lr = l6 & 15, lg = l6 >> 4;
    int node = tile * 64 + wv * 16 + lr;
    short8 b[4];
    const ushort_t* zr = z + (long)node * HID;
#pragma unroll
    for (int kt = 0; kt < 4; ++kt) b[kt] = *(const short8*)(zr + kt * 32 + lg * 8);
    __syncthreads();
#pragma unroll
    for (int nt = 0; nt < 8; ++nt) {
        f32x4 acc = (f32x4){0.f, 0.f, 0.f, 0.f};
        int brow = nt * 16 + lr;
#pragma unroll
        for (int kt = 0; kt < 4; ++kt) {
            short8 af = *(const short8*)&lBw[brow * HID + (((kt * 4 + lg) ^ (brow & 7)) << 3)];
            acc = __builtin_amdgcn_mfma_f32_16x16x32_bf16(af, b[kt], acc, 0, 0, 0);
        }
        f32x4 bv = *(const f32x4*)(b1 + l * HID2 + half * 128 + nt * 16 + lg * 4);
        s16x4 o;
#pragma unroll
        for (int r = 0; r < 4; ++r) o[r] = (short)f2b(fmaxf(acc[r] + bv[r], 0.f));
        *(s16x4*)(ibuf + (long)node * HID2 + half * 128 + nt * 16 + lg * 4) = o;
    }
}

// ---------------- mlp2: one 64-node tile/block, LDS weight half (A), BN stats via LDS ----
__global__ __launch_bounds__(256) void k_mlp2(const ushort_t* __restrict__ ibuf,
                                              const ushort_t* __restrict__ w2T,
                                              const float* __restrict__ b2,
                                              ushort_t* __restrict__ z2,
                                              float* __restrict__ bnstats, int l) {
    __shared__ __align__(16) short lBw[64 * HID2];  // 32 KB: 64 feats x K=256
    __shared__ float lStat[2][64];
    int half = blockIdx.x & 1;
    int tile = blockIdx.x >> 1;
    const ushort_t* wl = w2T + (long)l * HID * HID2 + (long)half * 64 * HID2;
    for (int c = threadIdx.x; c < 64 * HID2 / 8; c += 256) {
        int row = c >> 5, k0 = (c & 31) * 8;
        short8 v = *(const short8*)(wl + row * HID2 + k0);
        int gsw = (k0 >> 3) ^ (row & 7);
        *(short8*)&lBw[row * HID2 + gsw * 8] = v;
    }
    if (threadIdx.x < 128) lStat[threadIdx.x >> 6][threadIdx.x & 63] = 0.f;
    int wv = threadIdx.x >> 6, l6 = threadIdx.x & 63;
    int lr = l6 & 15, lg = l6 >> 4;
    int node = tile * 64 + wv * 16 + lr;
    bool valid = node < N_NODES;
    short8 b[8];
    const ushort_t* ir = ibuf + (long)node * HID2;
#pragma unroll
    for (int kt = 0; kt < 8; ++kt) b[kt] = *(const short8*)(ir + kt * 32 + lg * 8);
    __syncthreads();
#pragma unroll
    for (int nt = 0; nt < 4; ++nt) {
        f32x4 acc = (f32x4){0.f, 0.f, 0.f, 0.f};
        int brow = nt * 16 + lr;
#pragma unroll
        for (int kt = 0; kt < 8; ++kt) {
            short8 af = *(const short8*)&lBw[brow * HID2 + (((kt * 4 + lg) ^ (brow & 7)) << 3)];
            acc = __builtin_amdgcn_mfma_f32_16x16x32_bf16(af, b[kt], acc, 0, 0, 0);
        }
        f32x4 bv = *(const f32x4*)(b2 + l * HID + half * 64 + nt * 16 + lg * 4);
        s16x4 o;
#pragma unroll
        for (int r = 0; r < 4; ++r) {
            float v = acc[r] + bv[r];
            o[r] = (short)f2b(v);
            float s = valid ? v : 0.f, q = valid ? v * v : 0.f;
            s += __shfl_xor(s, 1); s += __shfl_xor(s, 2);
            s += __shfl_xor(s, 4); s += __shfl_xor(s, 8);
            q += __shfl_xor(q, 1); q += __shfl_xor(q, 2);
            q += __shfl_xor(q, 4); q += __shfl_xor(q, 8);
            if (lr == 0) {
                int f = nt * 16 + lg * 4 + r;  // feat within half [0,64)
                atomicAdd(&lStat[0][f], s);
                atomicAdd(&lStat[1][f], q);
            }
        }
        *(s16x4*)(z2 + (long)node * HID + half * 64 + nt * 16 + lg * 4) = o;
    }
    __syncthreads();
    if (threadIdx.x < 128) {
        int which = threadIdx.x >> 6, f = threadIdx.x & 63;
        atomicAdd(&bnstats[(which * NLAYER + l) * HID + half * 64 + f], lStat[which][f]);
    }
}

// ---------------- BN apply + residual + relu ----------------
__global__ __launch_bounds__(1024) void k_resid(const ushort_t* __restrict__ z2,
                                                const float* __restrict__ bnstats,
                                                const float* __restrict__ bng,
                                                const float* __restrict__ bnb,
                                                float* __restrict__ h,
                                                ushort_t* __restrict__ hb, int l) {
    long i = (long)blockIdx.x * 1024 + threadIdx.x;
    int c = (int)(i & (HID - 1));
    float inv = 1.f / (float)N_NODES;
    float mu = bnstats[l * HID + c] * inv;
    float var = bnstats[(NLAYER + l) * HID + c] * inv - mu * mu;
    float A = rsqrtf(var + 1e-5f) * bng[l * HID + c];
    float B = bnb[l * HID + c] - mu * A;
    float v = fmaf(b2f(z2[i]), A, B) + h[i];
    v = fmaxf(v, 0.f);
    h[i] = v;
    hb[i] = f2b(v);
}

// ---------------- pooling (per-block binary search for segment bounds) --------------
__global__ __launch_bounds__(512) void k_pool(const float* __restrict__ h,
                                              const int* __restrict__ batch,
                                              float* __restrict__ pooled,
                                              float* __restrict__ outp) {
    __shared__ float red[4][HID];
    __shared__ int sb[2];
    int g = blockIdx.x;
    if (threadIdx.x < 2) {
        int target = g + threadIdx.x;
        int lo = 0, hi = N_NODES;
        while (lo < hi) { int mid = (lo + hi) >> 1; if (batch[mid] < target) lo = mid + 1; else hi = mid; }
        sb[threadIdx.x] = lo;
    }
    __syncthreads();
    int st = sb[0], en = sb[1];
    int ch = threadIdx.x & 127, seg = threadIdx.x >> 7;
    float s = 0.f;
    for (int i = st + seg; i < en; i += 4) s += h[(long)i * HID + ch];
    red[seg][ch] = s;
    __syncthreads();
    if (seg == 0) {
        float p = (red[0][ch] + red[1][ch] + red[2][ch] + red[3][ch]) /
                  fmaxf((float)(en - st), 1.f);
        pooled[g * HID + ch] = p;
        outp[g * HID + ch] = p;
    }
}

// ---------------- output MLP ----------------
__global__ __launch_bounds__(128) void k_outmlp(const float* __restrict__ pooled,
                                                const float* __restrict__ w1,
                                                const float* __restrict__ b1,
                                                const float* __restrict__ w2,
                                                const float* __restrict__ b2,
                                                float* __restrict__ outl) {
    __shared__ float pr[HID];
    __shared__ float hid[64];
    int g = blockIdx.x, t = threadIdx.x;
    pr[t] = pooled[g * HID + t];
    __syncthreads();
    if (t < 64) {
        float a = b1[t];
        for (int k = 0; k < HID; ++k) a = fmaf(pr[k], w1[k * 64 + t], a);
        hid[t] = fmaxf(a, 0.f);
    }
    __syncthreads();
    float a = b2[t];
#pragma unroll
    for (int j = 0; j < 64; ++j) a = fmaf(hid[j], w2[j * HID + t], a);
    outl[g * HID + t] = a;
}

// =====================================================================================
extern "C" void kernel_launch(void* const* d_in, const int* in_sizes, int n_in,
                              void* d_out, int out_size, void* d_ws, size_t ws_size,
                              hipStream_t stream) {
    (void)in_sizes; (void)n_in; (void)out_size;
    const float* x      = (const float*)d_in[0];
    const int*   ei     = (const int*)d_in[1];
    const float* ea     = (const float*)d_in[2];
    const int*   batch  = (const int*)d_in[3];
    const float* node_w = (const float*)d_in[4];
    const float* node_b = (const float*)d_in[5];
    const float* edge_w = (const float*)d_in[6];
    const float* edge_b = (const float*)d_in[7];
    const float* epsv   = (const float*)d_in[8];
    const float* lin_w  = (const float*)d_in[9];
    const float* lin_b  = (const float*)d_in[10];
    const float* m1w    = (const float*)d_in[11];
    const float* m1b    = (const float*)d_in[12];
    const float* m2w    = (const float*)d_in[13];
    const float* m2b    = (const float*)d_in[14];
    const float* bng    = (const float*)d_in[15];
    const float* bnb    = (const float*)d_in[16];
    const float* ow1    = (const float*)d_in[17];
    const float* ob1    = (const float*)d_in[18];
    const float* ow2    = (const float*)d_in[19];
    const float* ob2    = (const float*)d_in[20];

    // NC thresholds recomputed for the CURRENT (aliased) layout:
    // NC=1 total ~252.9 MiB; NC=2 ~174.8 MiB; NC=4 ~135.7 MiB; NC=8 ~116.2 MiB
    const size_t MiB = 1024ull * 1024ull;
    int NC;
    if      (ws_size >= 253 * MiB) NC = 1;
    else if (ws_size >= 176 * MiB) NC = 2;
    else if (ws_size >= 137 * MiB) NC = 4;
    else                           NC = 8;
    int EC = (N_EDGES + NC - 1) / NC;

    char* ws = (char*)d_ws;
    size_t off = 0;
    auto alloc = [&](size_t bytes) -> char* {
        char* p = ws + off;
        off = (off + bytes + 255) & ~(size_t)255;
        return p;
    };
    float*    h       = (float*)alloc((size_t)NPAD * HID * 4);
    ushort_t* hb      = (ushort_t*)alloc((size_t)NPAD * HID * 2);
    ushort_t* z       = (ushort_t*)alloc((size_t)NPAD * HID * 2);   // reused as z2
    ushort_t* ibuf    = (ushort_t*)alloc((size_t)NPAD * HID2 * 2);  // aliased: zacc, perm
    ushort_t* ea_sb   = (ushort_t*)alloc((size_t)N_EDGES * EDGE_DIM * 2 + 64);
    ushort_t* g       = (ushort_t*)alloc((size_t)EC * HID * 2);
    int*      src_s   = (int*)alloc((size_t)N_EDGES * 4);
    // deg, cursor, bnstats contiguous -> one memset covers all three
    int*      deg     = (int*)alloc((size_t)N_NODES * 4);
    int*      cursor  = (int*)alloc((size_t)N_NODES * 4);
    float*    bnstats = (float*)alloc((size_t)2 * NLAYER * HID * 4);
    int*      offs    = (int*)alloc((size_t)N_NODES * 4);
    int*      bsum    = (int*)alloc(64 * 4);
    ushort_t* WcbT    = (ushort_t*)alloc((size_t)NLAYER * HID * 32 * 2);
    float*    cc      = (float*)alloc((size_t)NLAYER * HID * 4);
    ushort_t* w0T     = (ushort_t*)alloc((size_t)HID * IN_CH * 2);
    ushort_t* w1T     = (ushort_t*)alloc((size_t)NLAYER * HID2 * HID * 2);
    ushort_t* w2T     = (ushort_t*)alloc((size_t)NLAYER * HID * HID2 * 2);
    float*    pooled  = (float*)alloc((size_t)NGRAPH * HID * 4);
    float*    zacc    = (float*)ibuf;  // alias: chunked-edge accumulator (NC>1 only)
    int*      perm    = (int*)ibuf;    // alias: CSR build only
    ushort_t* z2      = z;

    size_t zero_bytes = (size_t)((char*)bnstats - (char*)deg) + (size_t)2 * NLAYER * HID * 4;
    (void)hipMemsetAsync(deg, 0, zero_bytes, stream);

    k_transpose_all<<<1280, 256, 0, stream>>>(node_w, m1w, m2w, w0T, w1T, w2T);
    k_combine<<<NLAYER, HID, 0, stream>>>(edge_w, edge_b, lin_w, lin_b, WcbT, cc);

    k_hist<<<N_EDGES / 1024, 256, 0, stream>>>(ei, deg);
    k_scan1<<<49, 1024, 0, stream>>>(deg, offs, bsum);
    k_scan2<<<1, 64, 0, stream>>>(bsum, 49);
    k_scan3<<<49, 1024, 0, stream>>>(offs, bsum);
    k_scatter1<<<N_EDGES / 1024, 256, 0, stream>>>(ei, offs, cursor, perm);
    k_gather<<<N_EDGES / 256, 256, 0, stream>>>(perm, ei, ea, src_s, ea_sb);

    k_node_enc<<<NPAD / 64, 256, 0, stream>>>(x, w0T, node_b, h, hb);

    for (int l = 0; l < NLAYER; ++l) {
        for (int c = 0; c < NC; ++c) {
            int ce0 = c * EC;
            int ce1 = (ce0 + EC < N_EDGES) ? (ce0 + EC) : N_EDGES;
            int nblk = (ce1 - ce0 + 255) / 256;
            int mode = (c == 0 ? 1 : 0) | (c == NC - 1 ? 2 : 0);
            k_edgegemm<<<nblk, 256, 0, stream>>>(ea_sb, WcbT, cc, g, l, ce0, ce1);
            k_edge2<<<(N_NODES + 7) / 8, 512, 0, stream>>>(g, src_s, offs, deg, h, hb,
                                                           epsv, zacc, z, l, ce0, ce1, mode);
        }
        k_mlp1<<<MT64 * 2, 256, 0, stream>>>(z, w1T, m1b, ibuf, l);
        k_mlp2<<<MT64 * 2, 256, 0, stream>>>(ibuf, w2T, m2b, z2, bnstats, l);
        k_resid<<<(N_NODES * HID) / 1024, 1024, 0, stream>>>(z2, bnstats, bng, bnb, h, hb, l);
    }

    k_pool<<<NGRAPH, 512, 0, stream>>>(h, batch, pooled, (float*)d_out + NGRAPH * HID);
    k_outmlp<<<NGRAPH, HID, 0, stream>>>(pooled, ow1, ob1, ow2, ob2, (float*)d_out);
}

// Round 19
// 997.243 us; speedup vs baseline: 1.1999x; 1.0063x over previous
//
#include <hip/hip_runtime.h>

#define N_NODES  50000
#define NPAD     50048
#define N_EDGES  640000
#define IN_CH    64
#define EDGE_DIM 16
#define HID      128
#define HID2     256
#define NLAYER   5
#define NGRAPH   128
#define MT64     (NPAD / 64)

typedef unsigned short ushort_t;
typedef __attribute__((ext_vector_type(8))) short short8;
typedef __attribute__((ext_vector_type(4))) short s16x4;
typedef __attribute__((ext_vector_type(4))) float f32x4;
typedef __attribute__((ext_vector_type(2))) float f32x2;
typedef __attribute__((ext_vector_type(4))) int i32x4;

__device__ __forceinline__ float b2f(ushort_t u) {
    union { unsigned v; float f; } x; x.v = ((unsigned)u) << 16; return x.f;
}
__device__ __forceinline__ ushort_t f2b(float f) {
    union { float f; unsigned u; } x; x.f = f;
    unsigned u = x.u;
    unsigned r = (u + 0x7FFFu + ((u >> 16) & 1u)) >> 16;
    return (ushort_t)r;
}

// ---------------- prep: all three weight transposes in one launch ----------------
__global__ void k_transpose_all(const float* __restrict__ w0,   // [IN_CH][HID]
                                const float* __restrict__ w1,   // [L][HID][HID2]
                                const float* __restrict__ w2,   // [L][HID2][HID]
                                ushort_t* __restrict__ w0T,
                                ushort_t* __restrict__ w1T,
                                ushort_t* __restrict__ w2T) {
    const long n0 = (long)IN_CH * HID;
    const long n1 = (long)NLAYER * HID * HID2;
    const long n2 = (long)NLAYER * HID2 * HID;
    long total = n0 + n1 + n2;
    for (long i = (long)blockIdx.x * blockDim.x + threadIdx.x; i < total;
         i += (long)gridDim.x * blockDim.x) {
        if (i < n0) {
            int k = (int)(i / HID), n = (int)(i - (long)k * HID);
            w0T[(long)n * IN_CH + k] = f2b(w0[i]);
        } else if (i < n0 + n1) {
            long j = i - n0;
            int b = (int)(j / ((long)HID * HID2));
            int rem = (int)(j - (long)b * HID * HID2);
            int k = rem / HID2, n = rem - k * HID2;
            w1T[(long)b * HID * HID2 + (long)n * HID + k] = f2b(w1[j]);
        } else {
            long j = i - n0 - n1;
            int b = (int)(j / ((long)HID2 * HID));
            int rem = (int)(j - (long)b * HID2 * HID);
            int k = rem / HID, n = rem - k * HID;
            w2T[(long)b * HID2 * HID + (long)n * HID2 + k] = f2b(w2[j]);
        }
    }
}

// WcbT bf16 [l][col=128][k=32 zero-padded] + cc f32
__global__ __launch_bounds__(128) void k_combine(const float* __restrict__ ew,
                                                 const float* __restrict__ eb,
                                                 const float* __restrict__ lw,
                                                 const float* __restrict__ lb,
                                                 ushort_t* __restrict__ WcbT,
                                                 float* __restrict__ cc) {
    int l = blockIdx.x, j = threadIdx.x;
    float accW[EDGE_DIM];
#pragma unroll
    for (int k = 0; k < EDGE_DIM; ++k) accW[k] = 0.f;
    float accc = 0.f;
    for (int i = 0; i < HID; ++i) {
        float lwv = lw[((long)l * HID + i) * HID + j];
        accc = fmaf(eb[i], lwv, accc);
#pragma unroll
        for (int k = 0; k < EDGE_DIM; ++k)
            accW[k] = fmaf(ew[k * HID + i], lwv, accW[k]);
    }
    ushort_t* wp = WcbT + ((long)l * HID + j) * 32;
#pragma unroll
    for (int k = 0; k < EDGE_DIM; ++k) wp[k] = f2b(accW[k]);
#pragma unroll
    for (int k = EDGE_DIM; k < 32; ++k) wp[k] = 0;
    cc[l * HID + j] = accc + lb[l * HID + j];
}

// ---------------- CSR build (4 edges/thread: 4 atomics in flight) ----------------
__global__ __launch_bounds__(256) void k_hist(const int* __restrict__ ei, int* __restrict__ deg) {
    int e0 = (blockIdx.x * 256 + threadIdx.x) * 4;
    if (e0 >= N_EDGES) return;
    i32x4 d = *(const i32x4*)(ei + N_EDGES + e0);
    atomicAdd(&deg[d.x], 1);
    atomicAdd(&deg[d.y], 1);
    atomicAdd(&deg[d.z], 1);
    atomicAdd(&deg[d.w], 1);
}

__global__ __launch_bounds__(1024) void k_scan1(const int* __restrict__ deg,
                                                int* __restrict__ offs, int* __restrict__ bsum) {
    __shared__ int s[1024];
    int i = blockIdx.x * 1024 + threadIdx.x;
    int v = (i < N_NODES) ? deg[i] : 0;
    s[threadIdx.x] = v;
    __syncthreads();
    for (int off = 1; off < 1024; off <<= 1) {
        int t = (threadIdx.x >= off) ? s[threadIdx.x - off] : 0;
        __syncthreads();
        s[threadIdx.x] += t;
        __syncthreads();
    }
    if (i < N_NODES) offs[i] = s[threadIdx.x] - v;  // exclusive
    if (threadIdx.x == 1023) bsum[blockIdx.x] = s[1023];
}

// 64-thread wave inclusive-scan over nb<=64 entries -> exclusive in place
__global__ void k_scan2(int* __restrict__ bsum, int nb) {
    int t = threadIdx.x;
    int v = (t < nb) ? bsum[t] : 0;
    int x = v;
#pragma unroll
    for (int off = 1; off < 64; off <<= 1) {
        int y = __shfl_up(x, off);
        if ((t & 63) >= off) x += y;
    }
    if (t < nb) bsum[t] = x - v;  // exclusive
}

__global__ __launch_bounds__(1024) void k_scan3(int* __restrict__ offs, const int* __restrict__ bsum) {
    int i = blockIdx.x * 1024 + threadIdx.x;
    if (i < N_NODES) offs[i] += bsum[blockIdx.x];
}

// pos computation + 4B perm scatter, 4 edges/thread (4 atomics+stores in flight)
__global__ __launch_bounds__(256) void k_scatter1(const int* __restrict__ ei,
                                                  const int* __restrict__ offs,
                                                  int* __restrict__ cursor,
                                                  int* __restrict__ perm) {
    int e0 = (blockIdx.x * 256 + threadIdx.x) * 4;
    if (e0 >= N_EDGES) return;
    i32x4 d = *(const i32x4*)(ei + N_EDGES + e0);
    int p0 = offs[d.x] + atomicAdd(&cursor[d.x], 1);
    int p1 = offs[d.y] + atomicAdd(&cursor[d.y], 1);
    int p2 = offs[d.z] + atomicAdd(&cursor[d.z], 1);
    int p3 = offs[d.w] + atomicAdd(&cursor[d.w], 1);
    perm[p0] = e0;
    perm[p1] = e0 + 1;
    perm[p2] = e0 + 2;
    perm[p3] = e0 + 3;
}

// gather reads, coalesced writes
__global__ __launch_bounds__(256) void k_gather(const int* __restrict__ perm,
                                                const int* __restrict__ ei,
                                                const float* __restrict__ ea,
                                                int* __restrict__ src_s,
                                                ushort_t* __restrict__ ea_sb) {
    int p = blockIdx.x * 256 + threadIdx.x;
    if (p >= N_EDGES) return;
    int e = perm[p];
    src_s[p] = ei[e];
    const f32x4* srcp = (const f32x4*)(ea + (long)e * EDGE_DIM);
    f32x4 v0 = srcp[0], v1 = srcp[1], v2 = srcp[2], v3 = srcp[3];
    short8 o0, o1;
#pragma unroll
    for (int j = 0; j < 4; ++j) {
        o0[j] = (short)f2b(v0[j]); o0[4 + j] = (short)f2b(v1[j]);
        o1[j] = (short)f2b(v2[j]); o1[4 + j] = (short)f2b(v3[j]);
    }
    short8* dst = (short8*)(ea_sb + (long)p * EDGE_DIM);
    dst[0] = o0;
    dst[1] = o1;
}

// ---------------- node encoder: h = relu(x @ node_w + node_b), f32 + bf16 out --------
__global__ __launch_bounds__(256) void k_node_enc(const float* __restrict__ x,
                                                  const ushort_t* __restrict__ w0T,
                                                  const float* __restrict__ nb,
                                                  float* __restrict__ h,
                                                  ushort_t* __restrict__ hb) {
    __shared__ __align__(16) short lB[HID * IN_CH];
    for (int c = threadIdx.x; c < HID * IN_CH / 8; c += 256) {
        int row = c >> 3, k0 = (c & 7) * 8;
        short8 v = *(const short8*)(w0T + row * IN_CH + k0);
        int g = (k0 >> 3) ^ (row & 7);
        *(short8*)&lB[row * IN_CH + g * 8] = v;
    }
    __syncthreads();
    int wv = threadIdx.x >> 6, l6 = threadIdx.x & 63;
    int lr = l6 & 15, lg = l6 >> 4;
    int grow = blockIdx.x * 64 + wv * 16 + lr;
    f32x4 acc[8];
#pragma unroll
    for (int nt = 0; nt < 8; ++nt) acc[nt] = (f32x4){0.f, 0.f, 0.f, 0.f};
#pragma unroll
    for (int kt = 0; kt < 2; ++kt) {
        int kk = kt * 32 + lg * 8;
        short8 a = {0, 0, 0, 0, 0, 0, 0, 0};
        if (grow < N_NODES) {
            const float* xr = x + (long)grow * IN_CH + kk;
            f32x4 v0 = *(const f32x4*)xr;
            f32x4 v1 = *(const f32x4*)(xr + 4);
#pragma unroll
            for (int j = 0; j < 4; ++j) { a[j] = (short)f2b(v0[j]); a[4 + j] = (short)f2b(v1[j]); }
        }
#pragma unroll
        for (int nt = 0; nt < 8; ++nt) {
            int brow = nt * 16 + lr;
            short8 b = *(const short8*)&lB[brow * IN_CH + (((kk >> 3) ^ (brow & 7)) << 3)];
            acc[nt] = __builtin_amdgcn_mfma_f32_16x16x32_bf16(a, b, acc[nt], 0, 0, 0);
        }
    }
    int orow0 = blockIdx.x * 64 + wv * 16 + lg * 4;
#pragma unroll
    for (int nt = 0; nt < 8; ++nt) {
        int col = nt * 16 + lr;
        float bias = nb[col];
#pragma unroll
        for (int r = 0; r < 4; ++r) {
            int row = orow0 + r;
            if (row < N_NODES) {
                float v = fmaxf(acc[nt][r] + bias, 0.f);
                h[(long)row * HID + col] = v;
                hb[(long)row * HID + col] = f2b(v);
            }
        }
    }
}

// ---------------- per-layer edge GEMM (chunk [ce0,ce1)) ----------------
__global__ __launch_bounds__(256) void k_edgegemm(const ushort_t* __restrict__ ea_sb,
                                                  const ushort_t* __restrict__ WcbT,
                                                  const float* __restrict__ cc,
                                                  ushort_t* __restrict__ g, int l,
                                                  int ce0, int ce1) {
    int wv = threadIdx.x >> 6, l6 = threadIdx.x & 63;
    int lr = l6 & 15, lg = l6 >> 4;
    short8 af[8];
    f32x4 cv[8];
    const ushort_t* wp = WcbT + (long)l * HID * 32;
#pragma unroll
    for (int nt = 0; nt < 8; ++nt) {
        af[nt] = *(const short8*)(wp + (nt * 16 + lr) * 32 + lg * 8);
        cv[nt] = *(const f32x4*)(cc + l * HID + nt * 16 + lg * 4);
    }
    for (int it = 0; it < 4; ++it) {
        int e0 = ce0 + blockIdx.x * 256 + wv * 64 + it * 16;
        int e = e0 + lr;
        short8 b = {0, 0, 0, 0, 0, 0, 0, 0};
        if (e < ce1 && lg < 2) b = *(const short8*)(ea_sb + (long)e * EDGE_DIM + lg * 8);
        f32x4 acc[8];
#pragma unroll
        for (int nt = 0; nt < 8; ++nt) acc[nt] = (f32x4){0.f, 0.f, 0.f, 0.f};
#pragma unroll
        for (int nt = 0; nt < 8; ++nt)
            acc[nt] = __builtin_amdgcn_mfma_f32_16x16x32_bf16(af[nt], b, acc[nt], 0, 0, 0);
        if (e < ce1) {
            ushort_t* gp = g + (long)(e - ce0) * HID + lg * 4;
#pragma unroll
            for (int nt = 0; nt < 8; ++nt) {
                s16x4 o;
#pragma unroll
                for (int r = 0; r < 4; ++r) o[r] = (short)f2b(acc[nt][r] + cv[nt][r]);
                *(s16x4*)(gp + nt * 16) = o;
            }
        }
    }
}

// ---------------- per-layer aggregation over chunk [ce0,ce1), 8 nodes/block --------
// 8-deep edge pipeline: 8 src loads then 16 independent 4B loads in flight.
__global__ __launch_bounds__(512) void k_edge2(const ushort_t* __restrict__ g,
                                               const int* __restrict__ src_s,
                                               const int* __restrict__ offs,
                                               const int* __restrict__ deg,
                                               const float* __restrict__ h,
                                               const ushort_t* __restrict__ hb,
                                               const float* __restrict__ epsv,
                                               float* __restrict__ zacc,
                                               ushort_t* __restrict__ z,
                                               int l, int ce0, int ce1, int mode) {
    int lane = threadIdx.x & 63;
    int node = blockIdx.x * 8 + (threadIdx.x >> 6);
    if (node >= N_NODES) return;
    bool first = mode & 1, last = (mode & 2) != 0;
    int ch0 = lane * 2;
    int s0 = offs[node];
    int dg = deg[node];
    int e_lo = max(s0, ce0);
    int e_hi = min(s0 + dg, ce1);
    if (e_lo >= e_hi && !first && !last) return;
    float a0 = 0.f, a1 = 0.f;
    int i = e_lo;
    for (; i + 8 <= e_hi; i += 8) {
        long eg = (long)(i - ce0);
        int ss[8];
#pragma unroll
        for (int j = 0; j < 8; ++j) ss[j] = src_s[i + j];
        unsigned gv[8], hv[8];
#pragma unroll
        for (int j = 0; j < 8; ++j) gv[j] = *(const unsigned*)(g + (eg + j) * HID + ch0);
#pragma unroll
        for (int j = 0; j < 8; ++j) hv[j] = *(const unsigned*)(hb + (long)ss[j] * HID + ch0);
#pragma unroll
        for (int j = 0; j < 8; ++j) {
            a0 += fmaxf(b2f((ushort_t)(hv[j] & 0xffff)) + b2f((ushort_t)(gv[j] & 0xffff)), 0.f);
            a1 += fmaxf(b2f((ushort_t)(hv[j] >> 16)) + b2f((ushort_t)(gv[j] >> 16)), 0.f);
        }
    }
    for (; i + 4 <= e_hi; i += 4) {
        long eg = (long)(i - ce0);
        int sa = src_s[i], sb_ = src_s[i + 1], sc_ = src_s[i + 2], sd_ = src_s[i + 3];
        unsigned ga = *(const unsigned*)(g + eg * HID + ch0);
        unsigned gb = *(const unsigned*)(g + (eg + 1) * HID + ch0);
        unsigned gc = *(const unsigned*)(g + (eg + 2) * HID + ch0);
        unsigned gd = *(const unsigned*)(g + (eg + 3) * HID + ch0);
        unsigned ha = *(const unsigned*)(hb + (long)sa * HID + ch0);
        unsigned hbv = *(const unsigned*)(hb + (long)sb_ * HID + ch0);
        unsigned hc = *(const unsigned*)(hb + (long)sc_ * HID + ch0);
        unsigned hd = *(const unsigned*)(hb + (long)sd_ * HID + ch0);
        a0 += fmaxf(b2f((ushort_t)(ha & 0xffff)) + b2f((ushort_t)(ga & 0xffff)), 0.f);
        a1 += fmaxf(b2f((ushort_t)(ha >> 16)) + b2f((ushort_t)(ga >> 16)), 0.f);
        a0 += fmaxf(b2f((ushort_t)(hbv & 0xffff)) + b2f((ushort_t)(gb & 0xffff)), 0.f);
        a1 += fmaxf(b2f((ushort_t)(hbv >> 16)) + b2f((ushort_t)(gb >> 16)), 0.f);
        a0 += fmaxf(b2f((ushort_t)(hc & 0xffff)) + b2f((ushort_t)(gc & 0xffff)), 0.f);
        a1 += fmaxf(b2f((ushort_t)(hc >> 16)) + b2f((ushort_t)(gc >> 16)), 0.f);
        a0 += fmaxf(b2f((ushort_t)(hd & 0xffff)) + b2f((ushort_t)(gd & 0xffff)), 0.f);
        a1 += fmaxf(b2f((ushort_t)(hd >> 16)) + b2f((ushort_t)(gd >> 16)), 0.f);
    }
    for (; i < e_hi; ++i) {
        long eg = (long)(i - ce0);
        int s = src_s[i];
        unsigned gv = *(const unsigned*)(g + eg * HID + ch0);
        unsigned hv = *(const unsigned*)(hb + (long)s * HID + ch0);
        a0 += fmaxf(b2f((ushort_t)(hv & 0xffff)) + b2f((ushort_t)(gv & 0xffff)), 0.f);
        a1 += fmaxf(b2f((ushort_t)(hv >> 16)) + b2f((ushort_t)(gv >> 16)), 0.f);
    }
    if (!first) {
        f32x2 p = *(const f32x2*)(zacc + (long)node * HID + ch0);
        a0 += p[0]; a1 += p[1];
    }
    if (last) {
        float ep1 = 1.f + epsv[l];
        f32x2 hn = *(const f32x2*)(h + (long)node * HID + ch0);
        unsigned zz = (unsigned)f2b(fmaf(ep1, hn[0], a0)) |
                      ((unsigned)f2b(fmaf(ep1, hn[1], a1)) << 16);
        *(unsigned*)(z + (long)node * HID + ch0) = zz;
    } else {
        *(f32x2*)(zacc + (long)node * HID + ch0) = (f32x2){a0, a1};
    }
}

// ---------------- mlp1: one 64-node tile/block, LDS weight half (A), packed stores ----
__global__ __launch_bounds__(256) void k_mlp1(const ushort_t* __restrict__ z,
                                              const ushort_t* __restrict__ w1T,
                                              const float* __restrict__ b1,
                                              ushort_t* __restrict__ ibuf, int l) {
    __shared__ __align__(16) short lBw[128 * HID];  // 32 KB: 128 feats x K=128
    int half = blockIdx.x & 1;
    int tile = blockIdx.x >> 1;  // [0, MT64)
    const ushort_t* wl = w1T + (long)l * HID2 * HID + (long)half * 128 * HID;
    for (int c = threadIdx.x; c < 128 * HID / 8; c += 256) {
        int row = c >> 4, k0 = (c & 15) * 8;
        short8 v = *(const short8*)(wl + row * HID + k0);
        int gsw = (k0 >> 3) ^ (row & 7);
        *(short8*)&lBw[row * HID + gsw * 8] = v;
    }
    int wv = threadIdx.x >> 6, l6 = threadIdx.x & 63;
    int lr = l6 & 15, lg = l6 >> 4;
    int node = tile * 64 + wv * 16 + lr;
    short8 b[4];
    const ushort_t* zr = z + (long)node * HID;
#pragma unroll
    for (int kt = 0; kt < 4; ++kt) b[kt] = *(const short8*)(zr + kt * 32 + lg * 8);
    __syncthreads();
#pragma unroll
    for (int nt = 0; nt < 8; ++nt) {
        f32x4 acc = (f32x4){0.f, 0.f, 0.f, 0.f};
        int brow = nt * 16 + lr;
#pragma unroll
        for (int kt = 0; kt < 4; ++kt) {
            short8 af = *(const short8*)&lBw[brow * HID + (((kt * 4 + lg) ^ (brow & 7)) << 3)];
            acc = __builtin_amdgcn_mfma_f32_16x16x32_bf16(af, b[kt], acc, 0, 0, 0);
        }
        f32x4 bv = *(const f32x4*)(b1 + l * HID2 + half * 128 + nt * 16 + lg * 4);
        s16x4 o;
#pragma unroll
        for (int r = 0; r < 4; ++r) o[r] = (short)f2b(fmaxf(acc[r] + bv[r], 0.f));
        *(s16x4*)(ibuf + (long)node * HID2 + half * 128 + nt * 16 + lg * 4) = o;
    }
}

// ---------------- mlp2: one 64-node tile/block, LDS weight half (A), BN stats via LDS ----
__global__ __launch_bounds__(256) void k_mlp2(const ushort_t* __restrict__ ibuf,
                                              const ushort_t* __restrict__ w2T,
                                              const float* __restrict__ b2,
                                              ushort_t* __restrict__ z2,
                                              float* __restrict__ bnstats, int l) {
    __shared__ __align__(16) short lBw[64 * HID2];  // 32 KB: 64 feats x K=256
    __shared__ float lStat[2][64];
    int half = blockIdx.x & 1;
    int tile = blockIdx.x >> 1;
    const ushort_t* wl = w2T + (long)l * HID * HID2 + (long)half * 64 * HID2;
    for (int c = threadIdx.x; c < 64 * HID2 / 8; c += 256) {
        int row = c >> 5, k0 = (c & 31) * 8;
        short8 v = *(const short8*)(wl + row * HID2 + k0);
        int gsw = (k0 >> 3) ^ (row & 7);
        *(short8*)&lBw[row * HID2 + gsw * 8] = v;
    }
    if (threadIdx.x < 128) lStat[threadIdx.x >> 6][threadIdx.x & 63] = 0.f;
    int wv = threadIdx.x >> 6, l6 = threadIdx.x & 63;
    int lr = l6 & 15, lg = l6 >> 4;
    int node = tile * 64 + wv * 16 + lr;
    bool valid = node < N_NODES;
    short8 b[8];
    const ushort_t* ir = ibuf + (long)node * HID2;
#pragma unroll
    for (int kt = 0; kt < 8; ++kt) b[kt] = *(const short8*)(ir + kt * 32 + lg * 8);
    __syncthreads();
#pragma unroll
    for (int nt = 0; nt < 4; ++nt) {
        f32x4 acc = (f32x4){0.f, 0.f, 0.f, 0.f};
        int brow = nt * 16 + lr;
#pragma unroll
        for (int kt = 0; kt < 8; ++kt) {
            short8 af = *(const short8*)&lBw[brow * HID2 + (((kt * 4 + lg) ^ (brow & 7)) << 3)];
            acc = __builtin_amdgcn_mfma_f32_16x16x32_bf16(af, b[kt], acc, 0, 0, 0);
        }
        f32x4 bv = *(const f32x4*)(b2 + l * HID + half * 64 + nt * 16 + lg * 4);
        s16x4 o;
#pragma unroll
        for (int r = 0; r < 4; ++r) {
            float v = acc[r] + bv[r];
            o[r] = (short)f2b(v);
            float s = valid ? v : 0.f, q = valid ? v * v : 0.f;
            s += __shfl_xor(s, 1); s += __shfl_xor(s, 2);
            s += __shfl_xor(s, 4); s += __shfl_xor(s, 8);
            q += __shfl_xor(q, 1); q += __shfl_xor(q, 2);
            q += __shfl_xor(q, 4); q += __shfl_xor(q, 8);
            if (lr == 0) {
                int f = nt * 16 + lg * 4 + r;  // feat within half [0,64)
                atomicAdd(&lStat[0][f], s);
                atomicAdd(&lStat[1][f], q);
            }
        }
        *(s16x4*)(z2 + (long)node * HID + half * 64 + nt * 16 + lg * 4) = o;
    }
    __syncthreads();
    if (threadIdx.x < 128) {
        int which = threadIdx.x >> 6, f = threadIdx.x & 63;
        atomicAdd(&bnstats[(which * NLAYER + l) * HID + half * 64 + f], lStat[which][f]);
    }
}

// ---------------- BN apply + residual + relu ----------------
__global__ __launch_bounds__(1024) void k_resid(const ushort_t* __restrict__ z2,
                                                const float* __restrict__ bnstats,
                                                const float* __restrict__ bng,
                                                const float* __restrict__ bnb,
                                                float* __restrict__ h,
                                                ushort_t* __restrict__ hb, int l) {
    long i = (long)blockIdx.x * 1024 + threadIdx.x;
    int c = (int)(i & (HID - 1));
    float inv = 1.f / (float)N_NODES;
    float mu = bnstats[l * HID + c] * inv;
    float var = bnstats[(NLAYER + l) * HID + c] * inv - mu * mu;
    float A = rsqrtf(var + 1e-5f) * bng[l * HID + c];
    float B = bnb[l * HID + c] - mu * A;
    float v = fmaf(b2f(z2[i]), A, B) + h[i];
    v = fmaxf(v, 0.f);
    h[i] = v;
    hb[i] = f2b(v);
}

// ---------------- pooling (per-block binary search for segment bounds) --------------
__global__ __launch_bounds__(512) void k_pool(const float* __restrict__ h,
                                              const int* __restrict__ batch,
                                              float* __restrict__ pooled,
                                              float* __restrict__ outp) {
    __shared__ float red[4][HID];
    __shared__ int sb[2];
    int g = blockIdx.x;
    if (threadIdx.x < 2) {
        int target = g + threadIdx.x;
        int lo = 0, hi = N_NODES;
        while (lo < hi) { int mid = (lo + hi) >> 1; if (batch[mid] < target) lo = mid + 1; else hi = mid; }
        sb[threadIdx.x] = lo;
    }
    __syncthreads();
    int st = sb[0], en = sb[1];
    int ch = threadIdx.x & 127, seg = threadIdx.x >> 7;
    float s = 0.f;
    for (int i = st + seg; i < en; i += 4) s += h[(long)i * HID + ch];
    red[seg][ch] = s;
    __syncthreads();
    if (seg == 0) {
        float p = (red[0][ch] + red[1][ch] + red[2][ch] + red[3][ch]) /
                  fmaxf((float)(en - st), 1.f);
        pooled[g * HID + ch] = p;
        outp[g * HID + ch] = p;
    }
}

// ---------------- output MLP ----------------
__global__ __launch_bounds__(128) void k_outmlp(const float* __restrict__ pooled,
                                                const float* __restrict__ w1,
                                                const float* __restrict__ b1,
                                                const float* __restrict__ w2,
                                                const float* __restrict__ b2,
                                                float* __restrict__ outl) {
    __shared__ float pr[HID];
    __shared__ float hid[64];
    int g = blockIdx.x, t = threadIdx.x;
    pr[t] = pooled[g * HID + t];
    __syncthreads();
    if (t < 64) {
        float a = b1[t];
        for (int k = 0; k < HID; ++k) a = fmaf(pr[k], w1[k * 64 + t], a);
        hid[t] = fmaxf(a, 0.f);
    }
    __syncthreads();
    float a = b2[t];
#pragma unroll
    for (int j = 0; j < 64; ++j) a = fmaf(hid[j], w2[j * HID + t], a);
    outl[g * HID + t] = a;
}

// =====================================================================================
extern "C" void kernel_launch(void* const* d_in, const int* in_sizes, int n_in,
                              void* d_out, int out_size, void* d_ws, size_t ws_size,
                              hipStream_t stream) {
    (void)in_sizes; (void)n_in; (void)out_size;
    const float* x      = (const float*)d_in[0];
    const int*   ei     = (const int*)d_in[1];
    const float* ea     = (const float*)d_in[2];
    const int*   batch  = (const int*)d_in[3];
    const float* node_w = (const float*)d_in[4];
    const float* node_b = (const float*)d_in[5];
    const float* edge_w = (const float*)d_in[6];
    const float* edge_b = (const float*)d_in[7];
    const float* epsv   = (const float*)d_in[8];
    const float* lin_w  = (const float*)d_in[9];
    const float* lin_b  = (const float*)d_in[10];
    const float* m1w    = (const float*)d_in[11];
    const float* m1b    = (const float*)d_in[12];
    const float* m2w    = (const float*)d_in[13];
    const float* m2b    = (const float*)d_in[14];
    const float* bng    = (const float*)d_in[15];
    const float* bnb    = (const float*)d_in[16];
    const float* ow1    = (const float*)d_in[17];
    const float* ob1    = (const float*)d_in[18];
    const float* ow2    = (const float*)d_in[19];
    const float* ob2    = (const float*)d_in[20];

    // NC thresholds for the CURRENT (aliased) layout:
    // NC=1 total ~252.9 MiB; NC=2 ~174.8 MiB; NC=4 ~135.7 MiB; NC=8 ~116.2 MiB
    const size_t MiB = 1024ull * 1024ull;
    int NC;
    if      (ws_size >= 253 * MiB) NC = 1;
    else if (ws_size >= 176 * MiB) NC = 2;
    else if (ws_size >= 137 * MiB) NC = 4;
    else                           NC = 8;
    int EC = (N_EDGES + NC - 1) / NC;

    char* ws = (char*)d_ws;
    size_t off = 0;
    auto alloc = [&](size_t bytes) -> char* {
        char* p = ws + off;
        off = (off + bytes + 255) & ~(size_t)255;
        return p;
    };
    float*    h       = (float*)alloc((size_t)NPAD * HID * 4);
    ushort_t* hb      = (ushort_t*)alloc((size_t)NPAD * HID * 2);
    ushort_t* z       = (ushort_t*)alloc((size_t)NPAD * HID * 2);   // reused as z2
    ushort_t* ibuf    = (ushort_t*)alloc((size_t)NPAD * HID2 * 2);  // aliased: zacc, perm
    ushort_t* ea_sb   = (ushort_t*)alloc((size_t)N_EDGES * EDGE_DIM * 2 + 64);
    ushort_t* g       = (ushort_t*)alloc((size_t)EC * HID * 2);
    int*      src_s   = (int*)alloc((size_t)N_EDGES * 4);
    // deg, cursor, bnstats contiguous -> one memset covers all three
    int*      deg     = (int*)alloc((size_t)N_NODES * 4);
    int*      cursor  = (int*)alloc((size_t)N_NODES * 4);
    float*    bnstats = (float*)alloc((size_t)2 * NLAYER * HID * 4);
    int*      offs    = (int*)alloc((size_t)N_NODES * 4);
    int*      bsum    = (int*)alloc(64 * 4);
    ushort_t* WcbT    = (ushort_t*)alloc((size_t)NLAYER * HID * 32 * 2);
    float*    cc      = (float*)alloc((size_t)NLAYER * HID * 4);
    ushort_t* w0T     = (ushort_t*)alloc((size_t)HID * IN_CH * 2);
    ushort_t* w1T     = (ushort_t*)alloc((size_t)NLAYER * HID2 * HID * 2);
    ushort_t* w2T     = (ushort_t*)alloc((size_t)NLAYER * HID * HID2 * 2);
    float*    pooled  = (float*)alloc((size_t)NGRAPH * HID * 4);
    float*    zacc    = (float*)ibuf;  // alias: chunked-edge accumulator (NC>1 only)
    int*      perm    = (int*)ibuf;    // alias: CSR build only
    ushort_t* z2      = z;

    size_t zero_bytes = (size_t)((char*)bnstats - (char*)deg) + (size_t)2 * NLAYER * HID * 4;
    (void)hipMemsetAsync(deg, 0, zero_bytes, stream);

    k_transpose_all<<<1280, 256, 0, stream>>>(node_w, m1w, m2w, w0T, w1T, w2T);
    k_combine<<<NLAYER, HID, 0, stream>>>(edge_w, edge_b, lin_w, lin_b, WcbT, cc);

    k_hist<<<N_EDGES / 1024, 256, 0, stream>>>(ei, deg);
    k_scan1<<<49, 1024, 0, stream>>>(deg, offs, bsum);
    k_scan2<<<1, 64, 0, stream>>>(bsum, 49);
    k_scan3<<<49, 1024, 0, stream>>>(offs, bsum);
    k_scatter1<<<N_EDGES / 1024, 256, 0, stream>>>(ei, offs, cursor, perm);
    k_gather<<<N_EDGES / 256, 256, 0, stream>>>(perm, ei, ea, src_s, ea_sb);

    k_node_enc<<<NPAD / 64, 256, 0, stream>>>(x, w0T, node_b, h, hb);

    for (int l = 0; l < NLAYER; ++l) {
        for (int c = 0; c < NC; ++c) {
            int ce0 = c * EC;
            int ce1 = (ce0 + EC < N_EDGES) ? (ce0 + EC) : N_EDGES;
            int nblk = (ce1 - ce0 + 255) / 256;
            int mode = (c == 0 ? 1 : 0) | (c == NC - 1 ? 2 : 0);
            k_edgegemm<<<nblk, 256, 0, stream>>>(ea_sb, WcbT, cc, g, l, ce0, ce1);
            k_edge2<<<(N_NODES + 7) / 8, 512, 0, stream>>>(g, src_s, offs, deg, h, hb,
                                                           epsv, zacc, z, l, ce0, ce1, mode);
        }
        k_mlp1<<<MT64 * 2, 256, 0, stream>>>(z, w1T, m1b, ibuf, l);
        k_mlp2<<<MT64 * 2, 256, 0, stream>>>(ibuf, w2T, m2b, z2, bnstats, l);
        k_resid<<<(N_NODES * HID) / 1024, 1024, 0, stream>>>(z2, bnstats, bng, bnb, h, hb, l);
    }

    k_pool<<<NGRAPH, 512, 0, stream>>>(h, batch, pooled, (float*)d_out + NGRAPH * HID);
    k_outmlp<<<NGRAPH, HID, 0, stream>>>(pooled, ow1, ob1, ow2, ob2, (float*)d_out);
}